// Round 4
// baseline (3790.089 us; speedup 1.0000x reference)
//
#include <hip/hip_runtime.h>
#include <hip/hip_bf16.h>
#include <math.h>

#define PW 160
#define PSQ 25600          // 160*160
#define NB 4
#define NX 307200          // NB*3*PSQ
#define NDIM 76800         // 3*PSQ
#define NBLK 512           // persistent grid: 128 tiles x 4 batches

// 10x20 output tile geometry
#define TY 10
#define TX 20
#define XW 26
#define XSZ 416            // 16*26
#define H1W 24
#define H2W 22
#define H2N 264
#define OUTN 200

typedef __attribute__((ext_vector_type(8))) short short8;
typedef __attribute__((ext_vector_type(4))) float float4v;

struct TS40 { float t[40]; };
struct MC40 { float m[40]; float A; };
struct PK { float c1[40]; float c2[40]; };

__device__ __forceinline__ short bf16s(float f) {
    return __builtin_bit_cast(short, __float2bfloat16(f));
}
__device__ __forceinline__ unsigned packbf(float a, float b) {
    return (unsigned)(unsigned short)bf16s(a) | ((unsigned)(unsigned short)bf16s(b) << 16);
}

// ---------------- time embedding
__global__ void emb_kernel(const float* __restrict__ wt, const float* __restrict__ bt,
                           float* __restrict__ emb, TS40 ts) {
    int r = blockIdx.x, k = threadIdx.x;   // 64 threads
    __shared__ float e64[64];
    float t = ts.t[r];
    int j = k & 31;
    float freq = expf(-0.29710775393471556f * (float)j);  // -ln(10000)/31
    float a = t * 999.0f * freq;
    e64[k] = (k < 32) ? sinf(a) : cosf(a);
    __syncthreads();
    if (k < 32) {
        float acc = bt[k];
        #pragma unroll 8
        for (int q = 0; q < 64; q++) acc += e64[q] * wt[q * 32 + k];
        emb[r * 32 + k] = acc;
    }
}

// ---------------- repack weights into MFMA A-fragment order (bf16)
__global__ void repack_kernel(const float* __restrict__ w1, const float* __restrict__ w2,
                              const float* __restrict__ w3, short* __restrict__ w1p,
                              short* __restrict__ w2p, short* __restrict__ w3p) {
    int tid = blockIdx.x * 256 + threadIdx.x;
    if (tid < 9216) {
        int j = tid & 7, co = (tid >> 3) & 31, q4 = tid >> 8;
        int tap = q4 >> 2, quad = q4 & 3, ci = quad * 8 + j;
        w2p[tid] = bf16s(w2[(co * 32 + ci) * 9 + tap]);
    }
    if (tid < 4608) {
        int j = tid & 7, co = (tid >> 3) & 15, q4 = tid >> 7;
        int tap = q4 >> 2, quad = q4 & 3, ci = quad * 8 + j;
        float v = (co < 3) ? w3[(co * 32 + ci) * 9 + tap] : 0.0f;
        w3p[tid] = bf16s(v);
    }
    if (tid < 1024) {
        int j = tid & 7, co = (tid >> 3) & 31, quad = tid >> 8;
        int k = quad * 8 + j;
        float v = 0.0f;
        if (k < 27) { int tap = (k * 11) >> 5; int ci = k - tap * 3; v = w1[(co * 3 + ci) * 9 + tap]; }
        w1p[tid] = bf16s(v);
    }
}

// ---------------- persistent kernel: all 40 RK stages, one launch.
// Each block owns one (tile,batch) for the whole ODE solve. Cross-block halo
// dependency handled by a device-scope grid barrier per stage (one-shot
// counters, no reuse). teps (conv1 of eps) computed in-kernel once and held
// in registers; conv weights fragments held in registers.
__global__ __launch_bounds__(256, 2) void persist_kernel(
    float* __restrict__ x0, float* __restrict__ xacc, float* __restrict__ xst,
    const short* __restrict__ w1p, const short* __restrict__ w2p,
    const short* __restrict__ w3p, const float* __restrict__ b1,
    const float* __restrict__ b2, const float* __restrict__ b3,
    const float* __restrict__ emb, const float* __restrict__ epsin,
    float* __restrict__ Sacc, unsigned* __restrict__ bars,
    PK pk, float dt) {
    const int bid = blockIdx.x;             // 0..127
    const int tile = ((bid & 7) << 4) | (bid >> 3);   // XCD-aware swizzle (bijective)
    const int b = blockIdx.y;
    const int oy = (tile >> 3) * TY, ox = (tile & 7) * TX;
    const int tid = threadIdx.x;
    const int lane = tid & 63, wv = tid >> 6;
    const int n = lane & 15, quad = lane >> 4;

    __shared__ __align__(16) char smem[77088];
    short* sH1 = (short*)smem;                  // 336*64B = 21504
    short* sD1 = (short*)(smem + 21504);        // 21504
    short* sH2 = (short*)(smem + 43008);        // 264*64B = 16896
    short* sD2 = (short*)(smem + 59904);        // 16896
    short* sX  = (short*)(smem + 43008);        // bf16 x-tile (aliases sH2; dead after ph1)
    float* sOut = (float*)smem;                 // 4800B (ph3+) — aliases sH1 (dead after ph2)
    float* sBE = (float*)(smem + 76800);        // 32 f (per-stage)
    float* sB2 = (float*)(smem + 76928);        // 32 f
    float* sB3 = (float*)(smem + 77056);        // 3 f
    float* wsum = (float*)(smem + 77068);       // 4 f

    float myb1 = (tid < 32) ? b1[tid] : 0.0f;
    if (tid < 32) sB2[tid] = b2[tid];
    if (tid < 3) sB3[tid] = b3[tid];

    // ---- conv1 fragment setup (shared by teps precompute and phase 1)
    int koff[8], kval[8];
    #pragma unroll
    for (int j = 0; j < 8; ++j) {
        int k = quad * 8 + j;
        kval[j] = (k < 27);
        int tap = (k * 11) >> 5; if (k >= 27) tap = 0;
        int ci = k - tap * 3;
        int dy = (tap * 11) >> 5, dx = tap - dy * 3;
        koff[j] = kval[j] ? (ci * XSZ + dy * XW + dx) : 0;
    }
    short8 a0 = *(const short8*)&w1p[(quad * 32 + n) * 8];
    short8 a1w = *(const short8*)&w1p[(quad * 32 + 16 + n) * 8];

    // ---- teps precompute: raw conv1(eps) over this block's h1 region,
    // packed bf16 in registers, stage-invariant.
    for (int idx = tid; idx < 3 * XSZ; idx += 256) {
        int ci = idx / XSZ, p = idx - ci * XSZ;
        int ly = p / XW, lx = p - ly * XW;
        int gy = oy - 3 + ly, gx = ox - 3 + lx;
        float v = 0.0f;
        if (gy >= 0 && gy < PW && gx >= 0 && gx < PW)
            v = epsin[(size_t)ci * PSQ + gy * PW + gx];
        sX[idx] = bf16s(v);
    }
    __syncthreads();
    uint2 pt0[6], pt1[6];
    #pragma unroll
    for (int it = 0; it < 6; ++it) { pt0[it].x = pt0[it].y = 0u; pt1[it].x = pt1[it].y = 0u; }
    #pragma unroll
    for (int it = 0; it < 6; ++it) {
        int t = wv + it * 4;
        if (t < 21) {
            int p = t * 16 + n;
            int ry = p / H1W, rx = p - ry * H1W;
            int base = ry * XW + rx;
            short8 bb;
            #pragma unroll
            for (int j = 0; j < 8; ++j)
                bb[j] = kval[j] ? sX[koff[j] + base] : (short)0;
            float4v acc0 = {0.f, 0.f, 0.f, 0.f}, acc1 = {0.f, 0.f, 0.f, 0.f};
            acc0 = __builtin_amdgcn_mfma_f32_16x16x32_bf16(a0, bb, acc0, 0, 0, 0);
            acc1 = __builtin_amdgcn_mfma_f32_16x16x32_bf16(a1w, bb, acc1, 0, 0, 0);
            pt0[it].x = packbf(acc0[0], acc0[1]); pt0[it].y = packbf(acc0[2], acc0[3]);
            pt1[it].x = packbf(acc1[0], acc1[1]); pt1[it].y = packbf(acc1[2], acc1[3]);
        }
    }
    __syncthreads();   // sX (eps) dead

    // ---- epsin values for divergence dot (stage-invariant)
    float pf_e[3];
    #pragma unroll
    for (int rep = 0; rep < 3; ++rep) {
        int idx = tid + rep * 256;
        int v = (idx < 3 * OUTN);
        int idc = v ? idx : 0;
        int c = idc / OUTN, pp = idc - c * OUTN;
        int ry = pp / TX, rx = pp - ry * TX;
        pf_e[rep] = v ? epsin[(size_t)c * PSQ + (oy + ry) * PW + ox + rx] : 0.0f;
    }

    // ---- conv2/conv3 fragments (held in registers for all stages)
    short8 a2[9][2];
    #pragma unroll
    for (int tap = 0; tap < 9; ++tap) {
        a2[tap][0] = *(const short8*)&w2p[((tap * 4 + quad) * 32 + n) * 8];
        a2[tap][1] = *(const short8*)&w2p[((tap * 4 + quad) * 32 + 16 + n) * 8];
    }
    short8 a3[9];
    #pragma unroll
    for (int tap = 0; tap < 9; ++tap)
        a3[tap] = *(const short8*)&w3p[((tap * 4 + quad) * 16 + n) * 8];

    // ================= stage loop =================
    #pragma unroll 1
    for (int r = 0; r < 40; ++r) {
        const int mode = r & 3;
        const float c1 = pk.c1[r], c2 = pk.c2[r];
        const float* xin = (mode == 0) ? x0 : xst;
        if (tid < 32) sBE[tid] = myb1 + emb[r * 32 + tid];

        // ---- stage x region (zero-padded), bf16
        for (int idx = tid; idx < 3 * XSZ; idx += 256) {
            int ci = idx / XSZ, p = idx - ci * XSZ;
            int ly = p / XW, lx = p - ly * XW;
            int gy = oy - 3 + ly, gx = ox - 3 + lx;
            float v = 0.0f;
            if (gy >= 0 && gy < PW && gx >= 0 && gx < PW)
                v = xin[(size_t)(b * 3 + ci) * PSQ + gy * PW + gx];
            sX[idx] = bf16s(v);
        }
        __syncthreads();

        // ---- phase 1: conv1 over h1 region (336 px, 21 n-tiles)
        #pragma unroll
        for (int it = 0; it < 6; ++it) {
            int t = wv + it * 4;
            if (t < 21) {
                int p = t * 16 + n;
                int ry = p / H1W, rx = p - ry * H1W;
                int gy = oy - 2 + ry, gx = ox - 2 + rx;
                int inimg = (gy >= 0 && gy < PW && gx >= 0 && gx < PW);
                int base = ry * XW + rx;
                short8 bb;
                #pragma unroll
                for (int j = 0; j < 8; ++j)
                    bb[j] = kval[j] ? sX[koff[j] + base] : (short)0;
                float4v acc0 = {0.f, 0.f, 0.f, 0.f}, acc1 = {0.f, 0.f, 0.f, 0.f};
                acc0 = __builtin_amdgcn_mfma_f32_16x16x32_bf16(a0, bb, acc0, 0, 0, 0);
                acc1 = __builtin_amdgcn_mfma_f32_16x16x32_bf16(a1w, bb, acc1, 0, 0, 0);
                int swz = (p & 7) << 4;
                #pragma unroll
                for (int mt = 0; mt < 2; ++mt) {
                    float4v* ac = mt ? &acc1 : &acc0;
                    uint2 t2 = mt ? pt1[it] : pt0[it];
                    int co0 = mt * 16 + quad * 4;
                    unsigned ts4[4] = {t2.x & 0xFFFFu, t2.x >> 16, t2.y & 0xFFFFu, t2.y >> 16};
                    unsigned hv[4], dv[4];
                    #pragma unroll
                    for (int g = 0; g < 4; ++g) {
                        float pre = (*ac)[g] + sBE[co0 + g];
                        hv[g] = inimg ? (unsigned)(unsigned short)bf16s(fmaxf(pre, 0.0f)) : 0u;
                        dv[g] = (inimg && pre > 0.0f) ? ts4[g] : 0u;
                    }
                    uint2 hw, dw;
                    hw.x = hv[0] | (hv[1] << 16); hw.y = hv[2] | (hv[3] << 16);
                    dw.x = dv[0] | (dv[1] << 16); dw.y = dv[2] | (dv[3] << 16);
                    int byw = ((p << 6) | (co0 << 1)) ^ swz;
                    *(uint2*)((char*)sH1 + byw) = hw;
                    *(uint2*)((char*)sD1 + byw) = dw;
                }
            }
        }
        __syncthreads();

        // ---- phase 2: conv2 over h2 region (264 px, 17 n-tiles)
        for (int t = wv; t < 17; t += 4) {
            int p = t * 16 + n;
            int pc = p < H2N ? p : (H2N - 1);
            int ry = pc / H2W, rx = pc - ry * H2W;
            float4v aP0 = {0.f,0.f,0.f,0.f}, aP1 = {0.f,0.f,0.f,0.f};
            float4v aD0 = {0.f,0.f,0.f,0.f}, aD1 = {0.f,0.f,0.f,0.f};
            #pragma unroll
            for (int tap = 0; tap < 9; ++tap) {
                int dy = (tap * 11) >> 5, dx = tap - dy * 3;
                int q = (ry + dy) * H1W + rx + dx;
                int byr = ((q << 6) | (quad << 4)) ^ ((q & 7) << 4);
                short8 bp = *(const short8*)((const char*)sH1 + byr);
                short8 bd = *(const short8*)((const char*)sD1 + byr);
                aP0 = __builtin_amdgcn_mfma_f32_16x16x32_bf16(a2[tap][0], bp, aP0, 0, 0, 0);
                aP1 = __builtin_amdgcn_mfma_f32_16x16x32_bf16(a2[tap][1], bp, aP1, 0, 0, 0);
                aD0 = __builtin_amdgcn_mfma_f32_16x16x32_bf16(a2[tap][0], bd, aD0, 0, 0, 0);
                aD1 = __builtin_amdgcn_mfma_f32_16x16x32_bf16(a2[tap][1], bd, aD1, 0, 0, 0);
            }
            int gy = oy - 1 + ry, gx = ox - 1 + rx;
            int inimg = (gy >= 0 && gy < PW && gx >= 0 && gx < PW);
            if (p < H2N) {
                int swz = (p & 7) << 4;
                #pragma unroll
                for (int mt = 0; mt < 2; ++mt) {
                    float4v* acP = mt ? &aP1 : &aP0;
                    float4v* acD = mt ? &aD1 : &aD0;
                    int co0 = mt * 16 + quad * 4;
                    unsigned hv[4], dv[4];
                    #pragma unroll
                    for (int g = 0; g < 4; ++g) {
                        float pre = (*acP)[g] + sB2[co0 + g];
                        hv[g] = inimg ? (unsigned)(unsigned short)bf16s(fmaxf(pre, 0.0f)) : 0u;
                        dv[g] = (inimg && pre > 0.0f) ? (unsigned)(unsigned short)bf16s((*acD)[g]) : 0u;
                    }
                    uint2 hw, dw;
                    hw.x = hv[0] | (hv[1] << 16); hw.y = hv[2] | (hv[3] << 16);
                    dw.x = dv[0] | (dv[1] << 16); dw.y = dv[2] | (dv[3] << 16);
                    int byw = ((p << 6) | (co0 << 1)) ^ swz;
                    *(uint2*)((char*)sH2 + byw) = hw;
                    *(uint2*)((char*)sD2 + byw) = dw;
                }
            }
        }
        __syncthreads();

        // ---- prefetch final-phase operands (own region only; covered by ph3)
        float pf_x[3], pf_a[3], pf_x0[3];
        #pragma unroll
        for (int rep = 0; rep < 3; ++rep) {
            int idx = tid + rep * 256;
            int v = (idx < 3 * OUTN);
            int idc = v ? idx : 0;
            int c = idc / OUTN, pp = idc - c * OUTN;
            int ry = pp / TX, rx = pp - ry * TX;
            size_t gi = (size_t)(b * 3 + c) * PSQ + (oy + ry) * PW + ox + rx;
            pf_x[rep] = v ? xin[gi] : 0.0f;
            pf_a[rep] = 0.0f; pf_x0[rep] = 0.0f;
            if (mode >= 1) {
                pf_a[rep] = v ? xacc[gi] : 0.0f;
                pf_x0[rep] = v ? x0[gi] : 0.0f;
            }
        }

        // ---- phase 3: conv3 over out tile (200 px, 13 n-tiles) -> sOut
        for (int t = wv; t < 13; t += 4) {
            int p = t * 16 + n;
            int pc = p < OUTN ? p : (OUTN - 1);
            int ry = pc / TX, rx = pc - ry * TX;
            float4v aP = {0.f,0.f,0.f,0.f}, aD = {0.f,0.f,0.f,0.f};
            #pragma unroll
            for (int tap = 0; tap < 9; ++tap) {
                int dy = (tap * 11) >> 5, dx = tap - dy * 3;
                int q = (ry + dy) * H2W + rx + dx;
                int byr = ((q << 6) | (quad << 4)) ^ ((q & 7) << 4);
                short8 bp = *(const short8*)((const char*)sH2 + byr);
                short8 bd = *(const short8*)((const char*)sD2 + byr);
                aP = __builtin_amdgcn_mfma_f32_16x16x32_bf16(a3[tap], bp, aP, 0, 0, 0);
                aD = __builtin_amdgcn_mfma_f32_16x16x32_bf16(a3[tap], bd, aD, 0, 0, 0);
            }
            if (quad == 0 && p < OUTN) {
                #pragma unroll
                for (int c = 0; c < 3; ++c) {
                    sOut[c * OUTN + p] = aP[c] + sB3[c];
                    sOut[3 * OUTN + c * OUTN + p] = aD[c];
                }
            }
        }
        __syncthreads();

        // ---- final: drift + RK update + divergence
        float s = 0.0f;
        #pragma unroll
        for (int rep = 0; rep < 3; ++rep) {
            int idx = tid + rep * 256;
            if (idx < 3 * OUTN) {
                int c = idx / OUTN, pp = idx - c * OUTN;
                int ry = pp / TX, rx = pp - ry * TX;
                size_t gi = (size_t)(b * 3 + c) * PSQ + (oy + ry) * PW + ox + rx;
                float y = sOut[c * OUTN + pp];
                float d = sOut[3 * OUTN + c * OUTN + pp];
                float xv = pf_x[rep];
                float k = -c1 * xv - c2 * y;
                if (mode == 0) {
                    xacc[gi] = k;
                    xst[gi] = xv + 0.5f * dt * k;     // xin == x0 at stage 0
                } else if (mode == 1) {
                    xacc[gi] = pf_a[rep] + 2.0f * k;
                    xst[gi] = pf_x0[rep] + 0.5f * dt * k;
                } else if (mode == 2) {
                    xacc[gi] = pf_a[rep] + 2.0f * k;
                    xst[gi] = pf_x0[rep] + dt * k;
                } else {
                    x0[gi] = pf_x0[rep] + (dt / 6.0f) * (pf_a[rep] + k);
                }
                s += d * pf_e[rep];
            }
        }
        #pragma unroll
        for (int off = 32; off > 0; off >>= 1) s += __shfl_down(s, off);
        if (lane == 0) wsum[wv] = s;
        __syncthreads();
        if (tid == 0) atomicAdd(&Sacc[r * 4 + b], wsum[0] + wsum[1] + wsum[2] + wsum[3]);

        // ---- grid barrier (one-shot counter per stage; release/acquire)
        if (r < 39) {
            __syncthreads();
            if (tid == 0) {
                __threadfence();
                __hip_atomic_fetch_add(&bars[r], 1u, __ATOMIC_ACQ_REL, __HIP_MEMORY_SCOPE_AGENT);
                while (__hip_atomic_load(&bars[r], __ATOMIC_ACQUIRE, __HIP_MEMORY_SCOPE_AGENT) < NBLK)
                    __builtin_amdgcn_s_sleep(8);
                __threadfence();
            }
            __syncthreads();
        }
    }
}

// ---------------- sum z^2 per batch (parallel over 25 segments)
__global__ void sumz2_kernel(const float* __restrict__ x0, float* __restrict__ sumz2) {
    int b = blockIdx.x, seg = blockIdx.y, tid = threadIdx.x;
    const float* p = x0 + (size_t)b * NDIM + seg * 3072;
    float s = 0.0f;
    for (int i = tid; i < 3072; i += 256) { float v = p[i]; s += v * v; }
    #pragma unroll
    for (int off = 32; off > 0; off >>= 1) s += __shfl_down(s, off);
    __shared__ float wsum[4];
    if ((tid & 63) == 0) wsum[tid >> 6] = s;
    __syncthreads();
    if (tid == 0) atomicAdd(&sumz2[b], wsum[0] + wsum[1] + wsum[2] + wsum[3]);
}

// ---------------- final bpd
__global__ void bpd_kernel(const float* __restrict__ S, const float* __restrict__ sumz2,
                           float* __restrict__ out, MC40 mc) {
    int b = threadIdx.x;
    if (b >= NB) return;
    float lp = mc.A;
    for (int r = 0; r < 40; r++) lp -= mc.m[r] * S[r * 4 + b];
    float prior = -70574.479354f - 0.5f * sumz2[b];
    out[b] = -(prior + lp) * 1.8785164100960743e-5f;
}

extern "C" void kernel_launch(void* const* d_in, const int* in_sizes, int n_in,
                              void* d_out, int out_size, void* d_ws, size_t ws_size,
                              hipStream_t stream) {
    const float* patches = (const float*)d_in[0];
    const float* epsin = (const float*)d_in[1];
    const float* w1 = (const float*)d_in[2];
    const float* b1 = (const float*)d_in[3];
    const float* wt = (const float*)d_in[4];
    const float* bt = (const float*)d_in[5];
    const float* w2 = (const float*)d_in[6];
    const float* b2 = (const float*)d_in[7];
    const float* w3 = (const float*)d_in[8];
    const float* b3 = (const float*)d_in[9];
    float* outp = (float*)d_out;
    char* wsb = (char*)d_ws;

    float* Sbuf  = (float*)(wsb + 0);          // 160 f
    float* sumz2 = (float*)(wsb + 640);        // 4 f
    unsigned* bars = (unsigned*)(wsb + 768);   // 40 u32 (one-shot barrier counters)
    float* emb   = (float*)(wsb + 1024);       // 1280 f
    short* w1p   = (short*)(wsb + 6144);       // 1024 bf16
    short* w2p   = (short*)(wsb + 8192);       // 9216 bf16
    short* w3p   = (short*)(wsb + 26624);      // 4608 bf16
    float* x0    = (float*)(wsb + 1675264);    // NX f
    float* xacc  = (float*)(wsb + 2904064);
    float* xst   = (float*)(wsb + 4132864);    // end ~5.4 MB

    const double dt = (1.0 - 1e-5) / 10.0;
    TS40 ts; MC40 mc; PK pk;
    double A = 0.0;
    const double wgt[4] = {1.0, 2.0, 2.0, 1.0};
    for (int i = 0; i < 10; i++) {
        double t0 = 1e-5 + dt * i;
        double tr[4] = {t0, t0 + 0.5 * dt, t0 + 0.5 * dt, t0 + dt};
        for (int s = 0; s < 4; s++) {
            int r = i * 4 + s;
            double t = tr[s];
            double beta = 0.1 + 19.9 * t;
            double lmc = -0.25 * t * t * 19.9 - 0.05 * t;
            double stdv = 1.0 - exp(2.0 * lmc);
            double g2 = beta * (1.0 - exp(4.0 * lmc));
            double c2 = 0.5 * g2 / stdv;
            ts.t[r] = (float)t;
            pk.c1[r] = (float)(0.5 * beta);
            pk.c2[r] = (float)c2;
            double coef = dt / 6.0 * wgt[s];
            mc.m[r] = (float)(coef * c2);
            A += coef * (-0.5 * beta * (double)NDIM);
        }
    }
    mc.A = (float)A;

    hipMemsetAsync(wsb, 0, 928, stream);  // Sbuf + sumz2 + bars
    hipMemcpyAsync(x0, patches, NX * sizeof(float), hipMemcpyDeviceToDevice, stream);

    emb_kernel<<<40, 64, 0, stream>>>(wt, bt, emb, ts);
    repack_kernel<<<36, 256, 0, stream>>>(w1, w2, w3, w1p, w2p, w3p);

    persist_kernel<<<dim3(128, NB), 256, 0, stream>>>(
        x0, xacc, xst, w1p, w2p, w3p, b1, b2, b3,
        emb, epsin, Sbuf, bars, pk, (float)dt);

    sumz2_kernel<<<dim3(NB, 25), 256, 0, stream>>>(x0, sumz2);
    bpd_kernel<<<1, 64, 0, stream>>>(Sbuf, sumz2, outp, mc);
}

// Round 5
// 1830.575 us; speedup vs baseline: 2.0704x; 2.0704x over previous
//
#include <hip/hip_runtime.h>
#include <hip/hip_bf16.h>
#include <math.h>

#define PW 160
#define PSQ 25600          // 160*160
#define NB 4
#define NX 307200          // NB*3*PSQ
#define NDIM 76800         // 3*PSQ
#define NBLK 512           // persistent grid: 128 tiles x 4 batches

// 10x20 output tile geometry
#define TY 10
#define TX 20
#define XW 26
#define XSZ 416            // 16*26
#define H1W 24
#define H2W 22
#define H2N 264
#define OUTN 200

typedef __attribute__((ext_vector_type(8))) short short8;
typedef __attribute__((ext_vector_type(4))) float float4v;

struct TS40 { float t[40]; };
struct MC40 { float m[40]; float A; };
struct PK { float c1[40]; float c2[40]; };

__device__ __forceinline__ short bf16s(float f) {
    return __builtin_bit_cast(short, __float2bfloat16(f));
}
__device__ __forceinline__ unsigned packbf(float a, float b) {
    return (unsigned)(unsigned short)bf16s(a) | ((unsigned)(unsigned short)bf16s(b) << 16);
}

// ---------------- time embedding
__global__ void emb_kernel(const float* __restrict__ wt, const float* __restrict__ bt,
                           float* __restrict__ emb, TS40 ts) {
    int r = blockIdx.x, k = threadIdx.x;   // 64 threads
    __shared__ float e64[64];
    float t = ts.t[r];
    int j = k & 31;
    float freq = expf(-0.29710775393471556f * (float)j);  // -ln(10000)/31
    float a = t * 999.0f * freq;
    e64[k] = (k < 32) ? sinf(a) : cosf(a);
    __syncthreads();
    if (k < 32) {
        float acc = bt[k];
        #pragma unroll 8
        for (int q = 0; q < 64; q++) acc += e64[q] * wt[q * 32 + k];
        emb[r * 32 + k] = acc;
    }
}

// ---------------- repack weights into MFMA A-fragment order (bf16)
__global__ void repack_kernel(const float* __restrict__ w1, const float* __restrict__ w2,
                              const float* __restrict__ w3, short* __restrict__ w1p,
                              short* __restrict__ w2p, short* __restrict__ w3p) {
    int tid = blockIdx.x * 256 + threadIdx.x;
    if (tid < 9216) {
        int j = tid & 7, co = (tid >> 3) & 31, q4 = tid >> 8;
        int tap = q4 >> 2, quad = q4 & 3, ci = quad * 8 + j;
        w2p[tid] = bf16s(w2[(co * 32 + ci) * 9 + tap]);
    }
    if (tid < 4608) {
        int j = tid & 7, co = (tid >> 3) & 15, q4 = tid >> 7;
        int tap = q4 >> 2, quad = q4 & 3, ci = quad * 8 + j;
        float v = (co < 3) ? w3[(co * 32 + ci) * 9 + tap] : 0.0f;
        w3p[tid] = bf16s(v);
    }
    if (tid < 1024) {
        int j = tid & 7, co = (tid >> 3) & 31, quad = tid >> 8;
        int k = quad * 8 + j;
        float v = 0.0f;
        if (k < 27) { int tap = (k * 11) >> 5; int ci = k - tap * 3; v = w1[(co * 3 + ci) * 9 + tap]; }
        w1p[tid] = bf16s(v);
    }
}

// ---------------- persistent kernel: all 40 RK stages, one launch.
// Cross-block 3-px halo dependency handled by NEIGHBOR-ONLY flags (one-shot,
// store+poll, no RMW fan-in) + ping-pong xst buffers. Adjacent tiles provably
// stay in stage lockstep, so WAR on the recycled buffer is covered by the
// same RAW flags. teps (conv1 of eps) held in registers for all stages.
__global__ __launch_bounds__(256, 2) void persist_kernel(
    float* __restrict__ x0, float* __restrict__ xacc,
    float* __restrict__ xstA, float* __restrict__ xstB,
    const short* __restrict__ w1p, const short* __restrict__ w2p,
    const short* __restrict__ w3p, const float* __restrict__ b1,
    const float* __restrict__ b2, const float* __restrict__ b3,
    const float* __restrict__ emb, const float* __restrict__ epsin,
    float* __restrict__ Sacc, unsigned* __restrict__ flags,
    PK pk, float dt) {
    const int bid = blockIdx.x;             // 0..127
    const int tile = ((bid & 7) << 4) | (bid >> 3);   // XCD-aware swizzle (bijective)
    const int b = blockIdx.y;
    const int oy = (tile >> 3) * TY, ox = (tile & 7) * TX;
    const int tid = threadIdx.x;
    const int lane = tid & 63, wv = tid >> 6;
    const int n = lane & 15, quad = lane >> 4;

    __shared__ __align__(16) char smem[77088];
    short* sH1 = (short*)smem;                  // 336*64B = 21504
    short* sD1 = (short*)(smem + 21504);        // 21504
    short* sH2 = (short*)(smem + 43008);        // 264*64B = 16896
    short* sD2 = (short*)(smem + 59904);        // 16896
    short* sX  = (short*)(smem + 43008);        // bf16 x-tile (aliases sH2; dead after ph1)
    float* sOut = (float*)smem;                 // 4800B (ph3+) — aliases sH1 (dead after ph2)
    float* sBE = (float*)(smem + 76800);        // 32 f (per-stage)
    float* sB2 = (float*)(smem + 76928);        // 32 f
    float* sB3 = (float*)(smem + 77056);        // 3 f
    float* wsum = (float*)(smem + 77068);       // 4 f

    float myb1 = (tid < 32) ? b1[tid] : 0.0f;
    if (tid < 32) sB2[tid] = b2[tid];
    if (tid < 3) sB3[tid] = b3[tid];

    // ---- conv1 fragment setup (shared by teps precompute and phase 1)
    int koff[8], kval[8];
    #pragma unroll
    for (int j = 0; j < 8; ++j) {
        int k = quad * 8 + j;
        kval[j] = (k < 27);
        int tap = (k * 11) >> 5; if (k >= 27) tap = 0;
        int ci = k - tap * 3;
        int dy = (tap * 11) >> 5, dx = tap - dy * 3;
        koff[j] = kval[j] ? (ci * XSZ + dy * XW + dx) : 0;
    }
    short8 a0 = *(const short8*)&w1p[(quad * 32 + n) * 8];
    short8 a1w = *(const short8*)&w1p[(quad * 32 + 16 + n) * 8];

    // ---- teps precompute: raw conv1(eps) over this block's h1 region,
    // packed bf16 in registers, stage-invariant.
    for (int idx = tid; idx < 3 * XSZ; idx += 256) {
        int ci = idx / XSZ, p = idx - ci * XSZ;
        int ly = p / XW, lx = p - ly * XW;
        int gy = oy - 3 + ly, gx = ox - 3 + lx;
        float v = 0.0f;
        if (gy >= 0 && gy < PW && gx >= 0 && gx < PW)
            v = epsin[(size_t)ci * PSQ + gy * PW + gx];
        sX[idx] = bf16s(v);
    }
    __syncthreads();
    uint2 pt0[6], pt1[6];
    #pragma unroll
    for (int it = 0; it < 6; ++it) { pt0[it].x = pt0[it].y = 0u; pt1[it].x = pt1[it].y = 0u; }
    #pragma unroll
    for (int it = 0; it < 6; ++it) {
        int t = wv + it * 4;
        if (t < 21) {
            int p = t * 16 + n;
            int ry = p / H1W, rx = p - ry * H1W;
            int base = ry * XW + rx;
            short8 bb;
            #pragma unroll
            for (int j = 0; j < 8; ++j)
                bb[j] = kval[j] ? sX[koff[j] + base] : (short)0;
            float4v acc0 = {0.f, 0.f, 0.f, 0.f}, acc1 = {0.f, 0.f, 0.f, 0.f};
            acc0 = __builtin_amdgcn_mfma_f32_16x16x32_bf16(a0, bb, acc0, 0, 0, 0);
            acc1 = __builtin_amdgcn_mfma_f32_16x16x32_bf16(a1w, bb, acc1, 0, 0, 0);
            pt0[it].x = packbf(acc0[0], acc0[1]); pt0[it].y = packbf(acc0[2], acc0[3]);
            pt1[it].x = packbf(acc1[0], acc1[1]); pt1[it].y = packbf(acc1[2], acc1[3]);
        }
    }
    __syncthreads();   // sX (eps) dead

    // ---- epsin values for divergence dot (stage-invariant)
    float pf_e[3];
    #pragma unroll
    for (int rep = 0; rep < 3; ++rep) {
        int idx = tid + rep * 256;
        int v = (idx < 3 * OUTN);
        int idc = v ? idx : 0;
        int c = idc / OUTN, pp = idc - c * OUTN;
        int ry = pp / TX, rx = pp - ry * TX;
        pf_e[rep] = v ? epsin[(size_t)c * PSQ + (oy + ry) * PW + ox + rx] : 0.0f;
    }

    // ---- conv2/conv3 fragments (held in registers for all stages)
    short8 a2[9][2];
    #pragma unroll
    for (int tap = 0; tap < 9; ++tap) {
        a2[tap][0] = *(const short8*)&w2p[((tap * 4 + quad) * 32 + n) * 8];
        a2[tap][1] = *(const short8*)&w2p[((tap * 4 + quad) * 32 + 16 + n) * 8];
    }
    short8 a3[9];
    #pragma unroll
    for (int tap = 0; tap < 9; ++tap)
        a3[tap] = *(const short8*)&w3p[((tap * 4 + quad) * 16 + n) * 8];

    // ================= stage loop =================
    #pragma unroll 1
    for (int r = 0; r < 40; ++r) {
        const int mode = r & 3;
        const float c1 = pk.c1[r], c2 = pk.c2[r];
        // ping-pong: stage r reads buf[(r-1)&1] (x0 at mode 0), writes buf[r&1]
        const float* xin = (mode == 0) ? x0 : ((r & 1) ? xstA : xstB);
        float* outb = (r & 1) ? xstB : xstA;

        // ---- neighbor RAW wait: 8 adjacent tiles' stage r-1 flags
        if (r > 0) {
            if (tid < 8) {
                int k = tid + (tid >= 4);               // 0..8 skipping center
                int ty2 = (tile >> 3) + k / 3 - 1;
                int tx2 = (tile & 7) + k % 3 - 1;
                if (ty2 >= 0 && ty2 < 16 && tx2 >= 0 && tx2 < 8) {
                    const unsigned* f = &flags[(r - 1) * NBLK + b * 128 + ty2 * 8 + tx2];
                    while (__hip_atomic_load(f, __ATOMIC_RELAXED, __HIP_MEMORY_SCOPE_AGENT) == 0)
                        __builtin_amdgcn_s_sleep(2);
                }
                __threadfence();    // acquire: one invalidate after all polls
            }
            __syncthreads();
        }
        if (tid < 32) sBE[tid] = myb1 + emb[r * 32 + tid];

        // ---- stage x region (zero-padded), bf16
        for (int idx = tid; idx < 3 * XSZ; idx += 256) {
            int ci = idx / XSZ, p = idx - ci * XSZ;
            int ly = p / XW, lx = p - ly * XW;
            int gy = oy - 3 + ly, gx = ox - 3 + lx;
            float v = 0.0f;
            if (gy >= 0 && gy < PW && gx >= 0 && gx < PW)
                v = xin[(size_t)(b * 3 + ci) * PSQ + gy * PW + gx];
            sX[idx] = bf16s(v);
        }
        __syncthreads();

        // ---- phase 1: conv1 over h1 region (336 px, 21 n-tiles)
        #pragma unroll
        for (int it = 0; it < 6; ++it) {
            int t = wv + it * 4;
            if (t < 21) {
                int p = t * 16 + n;
                int ry = p / H1W, rx = p - ry * H1W;
                int gy = oy - 2 + ry, gx = ox - 2 + rx;
                int inimg = (gy >= 0 && gy < PW && gx >= 0 && gx < PW);
                int base = ry * XW + rx;
                short8 bb;
                #pragma unroll
                for (int j = 0; j < 8; ++j)
                    bb[j] = kval[j] ? sX[koff[j] + base] : (short)0;
                float4v acc0 = {0.f, 0.f, 0.f, 0.f}, acc1 = {0.f, 0.f, 0.f, 0.f};
                acc0 = __builtin_amdgcn_mfma_f32_16x16x32_bf16(a0, bb, acc0, 0, 0, 0);
                acc1 = __builtin_amdgcn_mfma_f32_16x16x32_bf16(a1w, bb, acc1, 0, 0, 0);
                int swz = (p & 7) << 4;
                #pragma unroll
                for (int mt = 0; mt < 2; ++mt) {
                    float4v* ac = mt ? &acc1 : &acc0;
                    uint2 t2 = mt ? pt1[it] : pt0[it];
                    int co0 = mt * 16 + quad * 4;
                    unsigned ts4[4] = {t2.x & 0xFFFFu, t2.x >> 16, t2.y & 0xFFFFu, t2.y >> 16};
                    unsigned hv[4], dv[4];
                    #pragma unroll
                    for (int g = 0; g < 4; ++g) {
                        float pre = (*ac)[g] + sBE[co0 + g];
                        hv[g] = inimg ? (unsigned)(unsigned short)bf16s(fmaxf(pre, 0.0f)) : 0u;
                        dv[g] = (inimg && pre > 0.0f) ? ts4[g] : 0u;
                    }
                    uint2 hw, dw;
                    hw.x = hv[0] | (hv[1] << 16); hw.y = hv[2] | (hv[3] << 16);
                    dw.x = dv[0] | (dv[1] << 16); dw.y = dv[2] | (dv[3] << 16);
                    int byw = ((p << 6) | (co0 << 1)) ^ swz;
                    *(uint2*)((char*)sH1 + byw) = hw;
                    *(uint2*)((char*)sD1 + byw) = dw;
                }
            }
        }
        __syncthreads();

        // ---- phase 2: conv2 over h2 region (264 px, 17 n-tiles)
        for (int t = wv; t < 17; t += 4) {
            int p = t * 16 + n;
            int pc = p < H2N ? p : (H2N - 1);
            int ry = pc / H2W, rx = pc - ry * H2W;
            float4v aP0 = {0.f,0.f,0.f,0.f}, aP1 = {0.f,0.f,0.f,0.f};
            float4v aD0 = {0.f,0.f,0.f,0.f}, aD1 = {0.f,0.f,0.f,0.f};
            #pragma unroll
            for (int tap = 0; tap < 9; ++tap) {
                int dy = (tap * 11) >> 5, dx = tap - dy * 3;
                int q = (ry + dy) * H1W + rx + dx;
                int byr = ((q << 6) | (quad << 4)) ^ ((q & 7) << 4);
                short8 bp = *(const short8*)((const char*)sH1 + byr);
                short8 bd = *(const short8*)((const char*)sD1 + byr);
                aP0 = __builtin_amdgcn_mfma_f32_16x16x32_bf16(a2[tap][0], bp, aP0, 0, 0, 0);
                aP1 = __builtin_amdgcn_mfma_f32_16x16x32_bf16(a2[tap][1], bp, aP1, 0, 0, 0);
                aD0 = __builtin_amdgcn_mfma_f32_16x16x32_bf16(a2[tap][0], bd, aD0, 0, 0, 0);
                aD1 = __builtin_amdgcn_mfma_f32_16x16x32_bf16(a2[tap][1], bd, aD1, 0, 0, 0);
            }
            int gy = oy - 1 + ry, gx = ox - 1 + rx;
            int inimg = (gy >= 0 && gy < PW && gx >= 0 && gx < PW);
            if (p < H2N) {
                int swz = (p & 7) << 4;
                #pragma unroll
                for (int mt = 0; mt < 2; ++mt) {
                    float4v* acP = mt ? &aP1 : &aP0;
                    float4v* acD = mt ? &aD1 : &aD0;
                    int co0 = mt * 16 + quad * 4;
                    unsigned hv[4], dv[4];
                    #pragma unroll
                    for (int g = 0; g < 4; ++g) {
                        float pre = (*acP)[g] + sB2[co0 + g];
                        hv[g] = inimg ? (unsigned)(unsigned short)bf16s(fmaxf(pre, 0.0f)) : 0u;
                        dv[g] = (inimg && pre > 0.0f) ? (unsigned)(unsigned short)bf16s((*acD)[g]) : 0u;
                    }
                    uint2 hw, dw;
                    hw.x = hv[0] | (hv[1] << 16); hw.y = hv[2] | (hv[3] << 16);
                    dw.x = dv[0] | (dv[1] << 16); dw.y = dv[2] | (dv[3] << 16);
                    int byw = ((p << 6) | (co0 << 1)) ^ swz;
                    *(uint2*)((char*)sH2 + byw) = hw;
                    *(uint2*)((char*)sD2 + byw) = dw;
                }
            }
        }
        __syncthreads();

        // ---- prefetch final-phase operands (own region only; covered by ph3)
        float pf_x[3], pf_a[3], pf_x0[3];
        #pragma unroll
        for (int rep = 0; rep < 3; ++rep) {
            int idx = tid + rep * 256;
            int v = (idx < 3 * OUTN);
            int idc = v ? idx : 0;
            int c = idc / OUTN, pp = idc - c * OUTN;
            int ry = pp / TX, rx = pp - ry * TX;
            size_t gi = (size_t)(b * 3 + c) * PSQ + (oy + ry) * PW + ox + rx;
            pf_x[rep] = v ? xin[gi] : 0.0f;
            pf_a[rep] = 0.0f; pf_x0[rep] = 0.0f;
            if (mode >= 1) {
                pf_a[rep] = v ? xacc[gi] : 0.0f;
                pf_x0[rep] = v ? x0[gi] : 0.0f;
            }
        }

        // ---- phase 3: conv3 over out tile (200 px, 13 n-tiles) -> sOut
        for (int t = wv; t < 13; t += 4) {
            int p = t * 16 + n;
            int pc = p < OUTN ? p : (OUTN - 1);
            int ry = pc / TX, rx = pc - ry * TX;
            float4v aP = {0.f,0.f,0.f,0.f}, aD = {0.f,0.f,0.f,0.f};
            #pragma unroll
            for (int tap = 0; tap < 9; ++tap) {
                int dy = (tap * 11) >> 5, dx = tap - dy * 3;
                int q = (ry + dy) * H2W + rx + dx;
                int byr = ((q << 6) | (quad << 4)) ^ ((q & 7) << 4);
                short8 bp = *(const short8*)((const char*)sH2 + byr);
                short8 bd = *(const short8*)((const char*)sD2 + byr);
                aP = __builtin_amdgcn_mfma_f32_16x16x32_bf16(a3[tap], bp, aP, 0, 0, 0);
                aD = __builtin_amdgcn_mfma_f32_16x16x32_bf16(a3[tap], bd, aD, 0, 0, 0);
            }
            if (quad == 0 && p < OUTN) {
                #pragma unroll
                for (int c = 0; c < 3; ++c) {
                    sOut[c * OUTN + p] = aP[c] + sB3[c];
                    sOut[3 * OUTN + c * OUTN + p] = aD[c];
                }
            }
        }
        __syncthreads();

        // ---- final: drift + RK update + divergence
        float s = 0.0f;
        #pragma unroll
        for (int rep = 0; rep < 3; ++rep) {
            int idx = tid + rep * 256;
            if (idx < 3 * OUTN) {
                int c = idx / OUTN, pp = idx - c * OUTN;
                int ry = pp / TX, rx = pp - ry * TX;
                size_t gi = (size_t)(b * 3 + c) * PSQ + (oy + ry) * PW + ox + rx;
                float y = sOut[c * OUTN + pp];
                float d = sOut[3 * OUTN + c * OUTN + pp];
                float xv = pf_x[rep];
                float k = -c1 * xv - c2 * y;
                if (mode == 0) {
                    xacc[gi] = k;
                    outb[gi] = xv + 0.5f * dt * k;     // xin == x0 at stage 0
                } else if (mode == 1) {
                    xacc[gi] = pf_a[rep] + 2.0f * k;
                    outb[gi] = pf_x0[rep] + 0.5f * dt * k;
                } else if (mode == 2) {
                    xacc[gi] = pf_a[rep] + 2.0f * k;
                    outb[gi] = pf_x0[rep] + dt * k;
                } else {
                    x0[gi] = pf_x0[rep] + (dt / 6.0f) * (pf_a[rep] + k);
                }
                s += d * pf_e[rep];
            }
        }
        #pragma unroll
        for (int off = 32; off > 0; off >>= 1) s += __shfl_down(s, off);
        if (lane == 0) wsum[wv] = s;
        __syncthreads();                    // all global writes issued + drained
        if (tid == 0) {
            atomicAdd(&Sacc[r * 4 + b], wsum[0] + wsum[1] + wsum[2] + wsum[3]);
            if (r < 39) {
                __threadfence();            // release: make writes agent-visible
                __hip_atomic_store(&flags[r * NBLK + b * 128 + tile], 1u,
                                   __ATOMIC_RELAXED, __HIP_MEMORY_SCOPE_AGENT);
            }
        }
    }
}

// ---------------- sum z^2 per batch (parallel over 25 segments)
__global__ void sumz2_kernel(const float* __restrict__ x0, float* __restrict__ sumz2) {
    int b = blockIdx.x, seg = blockIdx.y, tid = threadIdx.x;
    const float* p = x0 + (size_t)b * NDIM + seg * 3072;
    float s = 0.0f;
    for (int i = tid; i < 3072; i += 256) { float v = p[i]; s += v * v; }
    #pragma unroll
    for (int off = 32; off > 0; off >>= 1) s += __shfl_down(s, off);
    __shared__ float wsum[4];
    if ((tid & 63) == 0) wsum[tid >> 6] = s;
    __syncthreads();
    if (tid == 0) atomicAdd(&sumz2[b], wsum[0] + wsum[1] + wsum[2] + wsum[3]);
}

// ---------------- final bpd
__global__ void bpd_kernel(const float* __restrict__ S, const float* __restrict__ sumz2,
                           float* __restrict__ out, MC40 mc) {
    int b = threadIdx.x;
    if (b >= NB) return;
    float lp = mc.A;
    for (int r = 0; r < 40; r++) lp -= mc.m[r] * S[r * 4 + b];
    float prior = -70574.479354f - 0.5f * sumz2[b];
    out[b] = -(prior + lp) * 1.8785164100960743e-5f;
}

extern "C" void kernel_launch(void* const* d_in, const int* in_sizes, int n_in,
                              void* d_out, int out_size, void* d_ws, size_t ws_size,
                              hipStream_t stream) {
    const float* patches = (const float*)d_in[0];
    const float* epsin = (const float*)d_in[1];
    const float* w1 = (const float*)d_in[2];
    const float* b1 = (const float*)d_in[3];
    const float* wt = (const float*)d_in[4];
    const float* bt = (const float*)d_in[5];
    const float* w2 = (const float*)d_in[6];
    const float* b2 = (const float*)d_in[7];
    const float* w3 = (const float*)d_in[8];
    const float* b3 = (const float*)d_in[9];
    float* outp = (float*)d_out;
    char* wsb = (char*)d_ws;

    float* Sbuf  = (float*)(wsb + 0);          // 160 f
    float* sumz2 = (float*)(wsb + 640);        // 4 f
    float* emb   = (float*)(wsb + 1024);       // 1280 f
    short* w1p   = (short*)(wsb + 6144);       // 1024 bf16
    short* w2p   = (short*)(wsb + 8192);       // 9216 bf16
    short* w3p   = (short*)(wsb + 26624);      // 4608 bf16
    float* x0    = (float*)(wsb + 1675264);    // NX f
    float* xacc  = (float*)(wsb + 2904064);
    float* xstA  = (float*)(wsb + 4132864);
    float* xstB  = (float*)(wsb + 5361664);
    unsigned* flags = (unsigned*)(wsb + 6590464);  // 40*512 u32 = 81920 B

    const double dt = (1.0 - 1e-5) / 10.0;
    TS40 ts; MC40 mc; PK pk;
    double A = 0.0;
    const double wgt[4] = {1.0, 2.0, 2.0, 1.0};
    for (int i = 0; i < 10; i++) {
        double t0 = 1e-5 + dt * i;
        double tr[4] = {t0, t0 + 0.5 * dt, t0 + 0.5 * dt, t0 + dt};
        for (int s = 0; s < 4; s++) {
            int r = i * 4 + s;
            double t = tr[s];
            double beta = 0.1 + 19.9 * t;
            double lmc = -0.25 * t * t * 19.9 - 0.05 * t;
            double stdv = 1.0 - exp(2.0 * lmc);
            double g2 = beta * (1.0 - exp(4.0 * lmc));
            double c2 = 0.5 * g2 / stdv;
            ts.t[r] = (float)t;
            pk.c1[r] = (float)(0.5 * beta);
            pk.c2[r] = (float)c2;
            double coef = dt / 6.0 * wgt[s];
            mc.m[r] = (float)(coef * c2);
            A += coef * (-0.5 * beta * (double)NDIM);
        }
    }
    mc.A = (float)A;

    hipMemsetAsync(wsb, 0, 656, stream);                 // Sbuf + sumz2
    hipMemsetAsync(wsb + 6590464, 0, 81920, stream);     // flags (one-shot)
    hipMemcpyAsync(x0, patches, NX * sizeof(float), hipMemcpyDeviceToDevice, stream);

    emb_kernel<<<40, 64, 0, stream>>>(wt, bt, emb, ts);
    repack_kernel<<<36, 256, 0, stream>>>(w1, w2, w3, w1p, w2p, w3p);

    persist_kernel<<<dim3(128, NB), 256, 0, stream>>>(
        x0, xacc, xstA, xstB, w1p, w2p, w3p, b1, b2, b3,
        emb, epsin, Sbuf, flags, pk, (float)dt);

    sumz2_kernel<<<dim3(NB, 25), 256, 0, stream>>>(x0, sumz2);
    bpd_kernel<<<1, 64, 0, stream>>>(Sbuf, sumz2, outp, mc);
}

// Round 6
// 858.882 us; speedup vs baseline: 4.4128x; 2.1313x over previous
//
#include <hip/hip_runtime.h>
#include <hip/hip_bf16.h>
#include <math.h>

#define PW 160
#define PSQ 25600          // 160*160
#define NB 4
#define NX 307200          // NB*3*PSQ
#define NDIM 76800         // 3*PSQ

// 10x20 output tile geometry
#define TY 10
#define TX 20
#define XW 26
#define XSZ 416            // 16*26
#define H1W 24
#define H2W 22
#define H2N 264
#define OUTN 200

typedef __attribute__((ext_vector_type(8))) short short8;
typedef __attribute__((ext_vector_type(4))) float float4v;

struct TS40 { float t[40]; };
struct MC40 { float m[40]; float A; };

__device__ __forceinline__ short bf16s(float f) {
    return __builtin_bit_cast(short, __float2bfloat16(f));
}
__device__ __forceinline__ unsigned packbf(float a, float b) {
    return (unsigned)(unsigned short)bf16s(a) | ((unsigned)(unsigned short)bf16s(b) << 16);
}

// ---------------- time embedding
__global__ void emb_kernel(const float* __restrict__ wt, const float* __restrict__ bt,
                           float* __restrict__ emb, TS40 ts) {
    int r = blockIdx.x, k = threadIdx.x;   // 64 threads
    __shared__ float e64[64];
    float t = ts.t[r];
    int j = k & 31;
    float freq = expf(-0.29710775393471556f * (float)j);  // -ln(10000)/31
    float a = t * 999.0f * freq;
    e64[k] = (k < 32) ? sinf(a) : cosf(a);
    __syncthreads();
    if (k < 32) {
        float acc = bt[k];
        #pragma unroll 8
        for (int q = 0; q < 64; q++) acc += e64[q] * wt[q * 32 + k];
        emb[r * 32 + k] = acc;
    }
}

// ---------------- repack weights into MFMA A-fragment order (bf16)
__global__ void repack_kernel(const float* __restrict__ w1, const float* __restrict__ w2,
                              const float* __restrict__ w3, short* __restrict__ w1p,
                              short* __restrict__ w2p, short* __restrict__ w3p) {
    int tid = blockIdx.x * 256 + threadIdx.x;
    if (tid < 9216) {
        int j = tid & 7, co = (tid >> 3) & 31, q4 = tid >> 8;
        int tap = q4 >> 2, quad = q4 & 3, ci = quad * 8 + j;
        w2p[tid] = bf16s(w2[(co * 32 + ci) * 9 + tap]);
    }
    if (tid < 4608) {
        int j = tid & 7, co = (tid >> 3) & 15, q4 = tid >> 7;
        int tap = q4 >> 2, quad = q4 & 3, ci = quad * 8 + j;
        float v = (co < 3) ? w3[(co * 32 + ci) * 9 + tap] : 0.0f;
        w3p[tid] = bf16s(v);
    }
    if (tid < 1024) {
        int j = tid & 7, co = (tid >> 3) & 31, quad = tid >> 8;
        int k = quad * 8 + j;
        float v = 0.0f;
        if (k < 27) { int tap = (k * 11) >> 5; int ci = k - tap * 3; v = w1[(co * 3 + ci) * 9 + tap]; }
        w1p[tid] = bf16s(v);
    }
}

// ---------------- teps = raw conv1(eps), full image, bf16 [pix][32]
__global__ __launch_bounds__(256) void teps_conv1(
    const float* __restrict__ xin, const short* __restrict__ w1p,
    short* __restrict__ outH) {
    const int tile = blockIdx.x;
    const int ty0 = (tile / 10) * 16, tx0 = (tile % 10) * 16;
    const int tid = threadIdx.x;
    const int lane = tid & 63, wv = tid >> 6;
    const int n = lane & 15, quad = lane >> 4;
    __shared__ float sX[3 * 324];
    for (int idx = tid; idx < 3 * 324; idx += 256) {
        int ci = idx / 324, p = idx - ci * 324;
        int ly = p / 18, lx = p - ly * 18;
        int gy = ty0 + ly - 1, gx = tx0 + lx - 1;
        float v = 0.0f;
        if (gy >= 0 && gy < PW && gx >= 0 && gx < PW)
            v = xin[(size_t)ci * PSQ + gy * PW + gx];
        sX[idx] = v;
    }
    __syncthreads();
    int offj[8], valj[8];
    #pragma unroll
    for (int j = 0; j < 8; ++j) {
        int k = quad * 8 + j;
        valj[j] = (k < 27);
        int tap = (k * 11) >> 5; if (k >= 27) tap = 0;
        int ci = k - tap * 3;
        int dy = (tap * 11) >> 5, dx = tap - dy * 3;
        offj[j] = valj[j] ? (ci * 324 + dy * 18 + dx + n) : 0;
    }
    short8 a0 = *(const short8*)&w1p[(quad * 32 + n) * 8];
    short8 a1 = *(const short8*)&w1p[(quad * 32 + 16 + n) * 8];
    #pragma unroll
    for (int r = 0; r < 4; ++r) {
        int row = wv * 4 + r;
        short8 bb;
        #pragma unroll
        for (int j = 0; j < 8; ++j) {
            float v = valj[j] ? sX[offj[j] + row * 18] : 0.0f;
            bb[j] = bf16s(v);
        }
        float4v acc0 = {0.f, 0.f, 0.f, 0.f}, acc1 = {0.f, 0.f, 0.f, 0.f};
        acc0 = __builtin_amdgcn_mfma_f32_16x16x32_bf16(a0, bb, acc0, 0, 0, 0);
        acc1 = __builtin_amdgcn_mfma_f32_16x16x32_bf16(a1, bb, acc1, 0, 0, 0);
        int pix = (ty0 + row) * PW + tx0 + n;
        uint2 h0, h1v;
        h0.x = packbf(acc0[0], acc0[1]); h0.y = packbf(acc0[2], acc0[3]);
        h1v.x = packbf(acc1[0], acc1[1]); h1v.y = packbf(acc1[2], acc1[3]);
        *(uint2*)&outH[(size_t)pix * 32 + quad * 4] = h0;
        *(uint2*)&outH[(size_t)pix * 32 + 16 + quad * 4] = h1v;
    }
}

// ---------------- fully fused RK stage: conv1+conv2+conv3+divergence+RK update
// 10x20 tile; x 16x26, h1 14x24 (336px), h2 12x22 (264px)
// 512 threads (8 waves) per block, LDS 77104 B -> 2 blocks/CU = 4 waves/SIMD.
// Grid 512 blocks = exactly 2/CU everywhere (one balanced scheduling round).
__global__ __launch_bounds__(512, 4) void fused_stage(
    const float* __restrict__ xin, float* __restrict__ x0,
    float* __restrict__ xacc, float* __restrict__ xst,
    const short* __restrict__ w1p, const short* __restrict__ w2p,
    const short* __restrict__ w3p, const float* __restrict__ b1,
    const float* __restrict__ b2, const float* __restrict__ b3,
    const float* __restrict__ embr, const short* __restrict__ tepsb,
    const float* __restrict__ epsin, float* __restrict__ Sacc,
    float c1, float c2, float dt, int mode) {
    const int bid = blockIdx.x;             // 0..127
    const int tile = ((bid & 7) << 4) | (bid >> 3);   // XCD-aware swizzle (bijective)
    const int b = blockIdx.y;
    const int oy = (tile >> 3) * TY, ox = (tile & 7) * TX;
    const int tid = threadIdx.x;
    const int lane = tid & 63, wv = tid >> 6;          // wv 0..7
    const int n = lane & 15, quad = lane >> 4;

    __shared__ __align__(16) char smem[77104];
    short* sH1 = (short*)smem;                  // 336*64B = 21504
    short* sD1 = (short*)(smem + 21504);        // 21504
    short* sH2 = (short*)(smem + 43008);        // 264*64B = 16896
    short* sD2 = (short*)(smem + 59904);        // 16896
    short* sX  = (short*)(smem + 43008);        // bf16 x-tile (aliases sH2; dead after ph1)
    float* sOut = (float*)smem;                 // 4800B (ph3+) — aliases sH1 (dead after ph2)
    float* sBE = (float*)(smem + 76800);        // 32 f
    float* sB2 = (float*)(smem + 76928);        // 32 f
    float* sB3 = (float*)(smem + 77056);        // 3 f
    float* wsum = (float*)(smem + 77072);       // 8 f

    // ---- prefetch teps fragments for this block's ph1 iterations (stage-invariant)
    uint2 pt0[3], pt1[3];
    #pragma unroll
    for (int it = 0; it < 3; ++it) {
        int t = wv + it * 8;
        int tt = (t < 21) ? t : 0;
        int p = tt * 16 + n;
        int ry = p / H1W, rx = p - ry * H1W;
        int gy = oy - 2 + ry, gx = ox - 2 + rx;
        int ok = (t < 21) && gy >= 0 && gy < PW && gx >= 0 && gx < PW;
        size_t tbase = ok ? ((size_t)(gy * PW + gx) * 32) : 0;
        pt0[it] = *(const uint2*)&tepsb[tbase + quad * 4];
        pt1[it] = *(const uint2*)&tepsb[tbase + 16 + quad * 4];
    }

    if (tid < 32) { sBE[tid] = b1[tid] + embr[tid]; sB2[tid] = b2[tid]; }
    if (tid < 3) sB3[tid] = b3[tid];

    // ---- stage x region (zero-padded outside image), converted to bf16 once
    for (int idx = tid; idx < 3 * XSZ; idx += 512) {
        int ci = idx / XSZ, p = idx - ci * XSZ;
        int ly = p / XW, lx = p - ly * XW;
        int gy = oy - 3 + ly, gx = ox - 3 + lx;
        float v = 0.0f;
        if (gy >= 0 && gy < PW && gx >= 0 && gx < PW)
            v = xin[(size_t)(b * 3 + ci) * PSQ + gy * PW + gx];
        sX[idx] = bf16s(v);
    }
    __syncthreads();

    // ---- phase 1: conv1 over h1 region (336 px, 21 n-tiles)
    {
        int koff[8], kval[8];
        #pragma unroll
        for (int j = 0; j < 8; ++j) {
            int k = quad * 8 + j;
            kval[j] = (k < 27);
            int tap = (k * 11) >> 5; if (k >= 27) tap = 0;
            int ci = k - tap * 3;
            int dy = (tap * 11) >> 5, dx = tap - dy * 3;
            koff[j] = kval[j] ? (ci * XSZ + dy * XW + dx) : 0;
        }
        short8 a0 = *(const short8*)&w1p[(quad * 32 + n) * 8];
        short8 a1 = *(const short8*)&w1p[(quad * 32 + 16 + n) * 8];
        #pragma unroll
        for (int it = 0; it < 3; ++it) {
            int t = wv + it * 8;
            if (t < 21) {
                int p = t * 16 + n;                // < 336 always
                int ry = p / H1W, rx = p - ry * H1W;
                int gy = oy - 2 + ry, gx = ox - 2 + rx;
                int inimg = (gy >= 0 && gy < PW && gx >= 0 && gx < PW);
                int base = ry * XW + rx;
                short8 bb;
                #pragma unroll
                for (int j = 0; j < 8; ++j)
                    bb[j] = kval[j] ? sX[koff[j] + base] : (short)0;
                float4v acc0 = {0.f, 0.f, 0.f, 0.f}, acc1 = {0.f, 0.f, 0.f, 0.f};
                acc0 = __builtin_amdgcn_mfma_f32_16x16x32_bf16(a0, bb, acc0, 0, 0, 0);
                acc1 = __builtin_amdgcn_mfma_f32_16x16x32_bf16(a1, bb, acc1, 0, 0, 0);
                int swz = (p & 7) << 4;
                #pragma unroll
                for (int mt = 0; mt < 2; ++mt) {
                    float4v* ac = mt ? &acc1 : &acc0;
                    uint2 t2 = mt ? pt1[it] : pt0[it];
                    int co0 = mt * 16 + quad * 4;
                    unsigned ts4[4] = {t2.x & 0xFFFFu, t2.x >> 16, t2.y & 0xFFFFu, t2.y >> 16};
                    unsigned hv[4], dv[4];
                    #pragma unroll
                    for (int g = 0; g < 4; ++g) {
                        float pre = (*ac)[g] + sBE[co0 + g];
                        hv[g] = inimg ? (unsigned)(unsigned short)bf16s(fmaxf(pre, 0.0f)) : 0u;
                        dv[g] = (inimg && pre > 0.0f) ? ts4[g] : 0u;
                    }
                    uint2 hw, dw;
                    hw.x = hv[0] | (hv[1] << 16); hw.y = hv[2] | (hv[3] << 16);
                    dw.x = dv[0] | (dv[1] << 16); dw.y = dv[2] | (dv[3] << 16);
                    int byw = ((p << 6) | (co0 << 1)) ^ swz;
                    *(uint2*)((char*)sH1 + byw) = hw;
                    *(uint2*)((char*)sD1 + byw) = dw;
                }
            }
        }
    }
    __syncthreads();

    // ---- phase 2: conv2 over h2 region (264 px, 17 n-tiles), 4-chain ILP
    {
        short8 a2[9][2];
        #pragma unroll
        for (int tap = 0; tap < 9; ++tap) {
            a2[tap][0] = *(const short8*)&w2p[((tap * 4 + quad) * 32 + n) * 8];
            a2[tap][1] = *(const short8*)&w2p[((tap * 4 + quad) * 32 + 16 + n) * 8];
        }
        for (int t = wv; t < 17; t += 8) {
            int p = t * 16 + n;
            int pc = p < H2N ? p : (H2N - 1);
            int ry = pc / H2W, rx = pc - ry * H2W;
            float4v aP0 = {0.f,0.f,0.f,0.f}, aP1 = {0.f,0.f,0.f,0.f};
            float4v aD0 = {0.f,0.f,0.f,0.f}, aD1 = {0.f,0.f,0.f,0.f};
            #pragma unroll
            for (int tap = 0; tap < 9; ++tap) {
                int dy = (tap * 11) >> 5, dx = tap - dy * 3;
                int q = (ry + dy) * H1W + rx + dx;
                int byr = ((q << 6) | (quad << 4)) ^ ((q & 7) << 4);
                short8 bp = *(const short8*)((const char*)sH1 + byr);
                short8 bd = *(const short8*)((const char*)sD1 + byr);
                aP0 = __builtin_amdgcn_mfma_f32_16x16x32_bf16(a2[tap][0], bp, aP0, 0, 0, 0);
                aP1 = __builtin_amdgcn_mfma_f32_16x16x32_bf16(a2[tap][1], bp, aP1, 0, 0, 0);
                aD0 = __builtin_amdgcn_mfma_f32_16x16x32_bf16(a2[tap][0], bd, aD0, 0, 0, 0);
                aD1 = __builtin_amdgcn_mfma_f32_16x16x32_bf16(a2[tap][1], bd, aD1, 0, 0, 0);
            }
            int gy = oy - 1 + ry, gx = ox - 1 + rx;
            int inimg = (gy >= 0 && gy < PW && gx >= 0 && gx < PW);
            if (p < H2N) {
                int swz = (p & 7) << 4;
                #pragma unroll
                for (int mt = 0; mt < 2; ++mt) {
                    float4v* acP = mt ? &aP1 : &aP0;
                    float4v* acD = mt ? &aD1 : &aD0;
                    int co0 = mt * 16 + quad * 4;
                    unsigned hv[4], dv[4];
                    #pragma unroll
                    for (int g = 0; g < 4; ++g) {
                        float pre = (*acP)[g] + sB2[co0 + g];
                        hv[g] = inimg ? (unsigned)(unsigned short)bf16s(fmaxf(pre, 0.0f)) : 0u;
                        dv[g] = (inimg && pre > 0.0f) ? (unsigned)(unsigned short)bf16s((*acD)[g]) : 0u;
                    }
                    uint2 hw, dw;
                    hw.x = hv[0] | (hv[1] << 16); hw.y = hv[2] | (hv[3] << 16);
                    dw.x = dv[0] | (dv[1] << 16); dw.y = dv[2] | (dv[3] << 16);
                    int byw = ((p << 6) | (co0 << 1)) ^ swz;
                    *(uint2*)((char*)sH2 + byw) = hw;
                    *(uint2*)((char*)sD2 + byw) = dw;
                }
            }
        }
    }
    __syncthreads();

    // ---- prefetch final-phase operands now (covered by ph3's MFMA work)
    float pf_x[2], pf_e[2], pf_a[2], pf_x0[2];
    #pragma unroll
    for (int rep = 0; rep < 2; ++rep) {
        int idx = tid + rep * 512;
        int v = (idx < 3 * OUTN);
        int idc = v ? idx : 0;
        int c = idc / OUTN, pp = idc - c * OUTN;
        int ry = pp / TX, rx = pp - ry * TX;
        int pix = (oy + ry) * PW + ox + rx;
        size_t gi = (size_t)(b * 3 + c) * PSQ + pix;
        pf_x[rep] = v ? xin[gi] : 0.0f;
        pf_e[rep] = v ? epsin[c * PSQ + pix] : 0.0f;
        pf_a[rep] = 0.0f; pf_x0[rep] = 0.0f;
        if (mode >= 1) {
            pf_a[rep] = v ? xacc[gi] : 0.0f;
            pf_x0[rep] = v ? x0[gi] : 0.0f;
        }
    }

    // ---- phase 3: conv3 over out tile (200 px, 13 n-tiles) -> sOut
    {
        short8 a3[9];
        #pragma unroll
        for (int tap = 0; tap < 9; ++tap)
            a3[tap] = *(const short8*)&w3p[((tap * 4 + quad) * 16 + n) * 8];
        for (int t = wv; t < 13; t += 8) {
            int p = t * 16 + n;
            int pc = p < OUTN ? p : (OUTN - 1);
            int ry = pc / TX, rx = pc - ry * TX;
            float4v aP = {0.f,0.f,0.f,0.f}, aD = {0.f,0.f,0.f,0.f};
            #pragma unroll
            for (int tap = 0; tap < 9; ++tap) {
                int dy = (tap * 11) >> 5, dx = tap - dy * 3;
                int q = (ry + dy) * H2W + rx + dx;
                int byr = ((q << 6) | (quad << 4)) ^ ((q & 7) << 4);
                short8 bp = *(const short8*)((const char*)sH2 + byr);
                short8 bd = *(const short8*)((const char*)sD2 + byr);
                aP = __builtin_amdgcn_mfma_f32_16x16x32_bf16(a3[tap], bp, aP, 0, 0, 0);
                aD = __builtin_amdgcn_mfma_f32_16x16x32_bf16(a3[tap], bd, aD, 0, 0, 0);
            }
            if (quad == 0 && p < OUTN) {
                #pragma unroll
                for (int c = 0; c < 3; ++c) {
                    sOut[c * OUTN + p] = aP[c] + sB3[c];
                    sOut[3 * OUTN + c * OUTN + p] = aD[c];
                }
            }
        }
    }
    __syncthreads();

    // ---- final: drift + RK update + divergence, all 512 threads, prefetched ops
    float s = 0.0f;
    #pragma unroll
    for (int rep = 0; rep < 2; ++rep) {
        int idx = tid + rep * 512;
        if (idx < 3 * OUTN) {
            int c = idx / OUTN, pp = idx - c * OUTN;
            int ry = pp / TX, rx = pp - ry * TX;
            int pix = (oy + ry) * PW + ox + rx;
            size_t gi = (size_t)(b * 3 + c) * PSQ + pix;
            float y = sOut[c * OUTN + pp];
            float d = sOut[3 * OUTN + c * OUTN + pp];
            float xv = pf_x[rep];
            float k = -c1 * xv - c2 * y;
            if (mode == 0) {
                xacc[gi] = k;
                xst[gi] = xv + 0.5f * dt * k;     // xin == x0 at stage 0
            } else if (mode == 1) {
                xacc[gi] = pf_a[rep] + 2.0f * k;
                xst[gi] = pf_x0[rep] + 0.5f * dt * k;
            } else if (mode == 2) {
                xacc[gi] = pf_a[rep] + 2.0f * k;
                xst[gi] = pf_x0[rep] + dt * k;
            } else {
                x0[gi] = pf_x0[rep] + (dt / 6.0f) * (pf_a[rep] + k);
            }
            s += d * pf_e[rep];
        }
    }
    #pragma unroll
    for (int off = 32; off > 0; off >>= 1) s += __shfl_down(s, off);
    if (lane == 0) wsum[wv] = s;
    __syncthreads();
    if (tid == 0) {
        float tot = 0.0f;
        #pragma unroll
        for (int w = 0; w < 8; ++w) tot += wsum[w];
        atomicAdd(&Sacc[b], tot);
    }
}

// ---------------- sum z^2 per batch (parallel over 25 segments)
__global__ void sumz2_kernel(const float* __restrict__ x0, float* __restrict__ sumz2) {
    int b = blockIdx.x, seg = blockIdx.y, tid = threadIdx.x;
    const float* p = x0 + (size_t)b * NDIM + seg * 3072;
    float s = 0.0f;
    for (int i = tid; i < 3072; i += 256) { float v = p[i]; s += v * v; }
    #pragma unroll
    for (int off = 32; off > 0; off >>= 1) s += __shfl_down(s, off);
    __shared__ float wsum[4];
    if ((tid & 63) == 0) wsum[tid >> 6] = s;
    __syncthreads();
    if (tid == 0) atomicAdd(&sumz2[b], wsum[0] + wsum[1] + wsum[2] + wsum[3]);
}

// ---------------- final bpd
__global__ void bpd_kernel(const float* __restrict__ S, const float* __restrict__ sumz2,
                           float* __restrict__ out, MC40 mc) {
    int b = threadIdx.x;
    if (b >= NB) return;
    float lp = mc.A;
    for (int r = 0; r < 40; r++) lp -= mc.m[r] * S[r * 4 + b];
    float prior = -70574.479354f - 0.5f * sumz2[b];
    out[b] = -(prior + lp) * 1.8785164100960743e-5f;
}

extern "C" void kernel_launch(void* const* d_in, const int* in_sizes, int n_in,
                              void* d_out, int out_size, void* d_ws, size_t ws_size,
                              hipStream_t stream) {
    const float* patches = (const float*)d_in[0];
    const float* epsin = (const float*)d_in[1];
    const float* w1 = (const float*)d_in[2];
    const float* b1 = (const float*)d_in[3];
    const float* wt = (const float*)d_in[4];
    const float* bt = (const float*)d_in[5];
    const float* w2 = (const float*)d_in[6];
    const float* b2 = (const float*)d_in[7];
    const float* w3 = (const float*)d_in[8];
    const float* b3 = (const float*)d_in[9];
    float* outp = (float*)d_out;
    char* wsb = (char*)d_ws;

    float* Sbuf  = (float*)(wsb + 0);          // 160 f
    float* sumz2 = (float*)(wsb + 640);        // 4 f
    float* emb   = (float*)(wsb + 1024);       // 1280 f
    short* w1p   = (short*)(wsb + 6144);       // 1024 bf16
    short* w2p   = (short*)(wsb + 8192);       // 9216 bf16
    short* w3p   = (short*)(wsb + 26624);      // 4608 bf16
    short* tepsb = (short*)(wsb + 36864);      // 819200 bf16
    float* x0    = (float*)(wsb + 1675264);    // NX f
    float* xacc  = (float*)(wsb + 2904064);
    float* xst   = (float*)(wsb + 4132864);    // end ~5.4 MB

    const double dt = (1.0 - 1e-5) / 10.0;
    TS40 ts; MC40 mc;
    float c1a[40], c2a[40];
    double A = 0.0;
    const double wgt[4] = {1.0, 2.0, 2.0, 1.0};
    for (int i = 0; i < 10; i++) {
        double t0 = 1e-5 + dt * i;
        double tr[4] = {t0, t0 + 0.5 * dt, t0 + 0.5 * dt, t0 + dt};
        for (int s = 0; s < 4; s++) {
            int r = i * 4 + s;
            double t = tr[s];
            double beta = 0.1 + 19.9 * t;
            double lmc = -0.25 * t * t * 19.9 - 0.05 * t;
            double stdv = 1.0 - exp(2.0 * lmc);
            double g2 = beta * (1.0 - exp(4.0 * lmc));
            double c2 = 0.5 * g2 / stdv;
            ts.t[r] = (float)t;
            c1a[r] = (float)(0.5 * beta);
            c2a[r] = (float)c2;
            double coef = dt / 6.0 * wgt[s];
            mc.m[r] = (float)(coef * c2);
            A += coef * (-0.5 * beta * (double)NDIM);
        }
    }
    mc.A = (float)A;

    hipMemsetAsync(wsb, 0, 656, stream);  // Sbuf + sumz2
    hipMemcpyAsync(x0, patches, NX * sizeof(float), hipMemcpyDeviceToDevice, stream);

    emb_kernel<<<40, 64, 0, stream>>>(wt, bt, emb, ts);
    repack_kernel<<<36, 256, 0, stream>>>(w1, w2, w3, w1p, w2p, w3p);
    teps_conv1<<<100, 256, 0, stream>>>(epsin, w1p, tepsb);

    for (int i = 0; i < 10; i++) {
        for (int s = 0; s < 4; s++) {
            int r = i * 4 + s;
            const float* xin = (s == 0) ? x0 : xst;
            fused_stage<<<dim3(128, NB), 512, 0, stream>>>(
                xin, x0, xacc, xst, w1p, w2p, w3p, b1, b2, b3,
                emb + r * 32, tepsb, epsin, Sbuf + r * 4,
                c1a[r], c2a[r], (float)dt, s);
        }
    }
    sumz2_kernel<<<dim3(NB, 25), 256, 0, stream>>>(x0, sumz2);
    bpd_kernel<<<1, 64, 0, stream>>>(Sbuf, sumz2, outp, mc);
}

// Round 7
// 849.993 us; speedup vs baseline: 4.4590x; 1.0105x over previous
//
#include <hip/hip_runtime.h>
#include <hip/hip_bf16.h>
#include <math.h>

#define PW 160
#define PSQ 25600          // 160*160
#define NB 4
#define NX 307200          // NB*3*PSQ
#define NDIM 76800         // 3*PSQ

// 10x20 output tile geometry
#define TY 10
#define TX 20
#define XW 26
#define XSZ 416            // 16*26
#define H1W 24
#define H2W 22
#define H2N 264
#define OUTN 200

typedef __attribute__((ext_vector_type(8))) short short8;
typedef __attribute__((ext_vector_type(4))) float float4v;

struct TS40 { float t[40]; };
struct MC40 { float m[40]; float A; };

__device__ __forceinline__ short bf16s(float f) {
    return __builtin_bit_cast(short, __float2bfloat16(f));
}
__device__ __forceinline__ unsigned packbf(float a, float b) {
    return (unsigned)(unsigned short)bf16s(a) | ((unsigned)(unsigned short)bf16s(b) << 16);
}

// ---------------- time embedding
__global__ void emb_kernel(const float* __restrict__ wt, const float* __restrict__ bt,
                           float* __restrict__ emb, TS40 ts) {
    int r = blockIdx.x, k = threadIdx.x;   // 64 threads
    __shared__ float e64[64];
    float t = ts.t[r];
    int j = k & 31;
    float freq = expf(-0.29710775393471556f * (float)j);  // -ln(10000)/31
    float a = t * 999.0f * freq;
    e64[k] = (k < 32) ? sinf(a) : cosf(a);
    __syncthreads();
    if (k < 32) {
        float acc = bt[k];
        #pragma unroll 8
        for (int q = 0; q < 64; q++) acc += e64[q] * wt[q * 32 + k];
        emb[r * 32 + k] = acc;
    }
}

// ---------------- repack weights into MFMA A-fragment order (bf16)
// Channel-slot permutation for LDS-resident activations (H1/D1/H2/D2):
//   slot c' = quad*8 + mt*4 + g  holds true channel c = mt*16 + quad*4 + g.
// So A-fragment k-element (quad,j) maps to true cin = (j>>2)*16 + quad*4 + (j&3).
__global__ void repack_kernel(const float* __restrict__ w1, const float* __restrict__ w2,
                              const float* __restrict__ w3, short* __restrict__ w1p,
                              short* __restrict__ w2p, short* __restrict__ w3p) {
    int tid = blockIdx.x * 256 + threadIdx.x;
    if (tid < 9216) {
        int j = tid & 7, co = (tid >> 3) & 31, q4 = tid >> 8;
        int tap = q4 >> 2, quad = q4 & 3;
        int ci = ((j >> 2) << 4) + quad * 4 + (j & 3);   // permuted slot -> true channel
        w2p[tid] = bf16s(w2[(co * 32 + ci) * 9 + tap]);
    }
    if (tid < 4608) {
        int j = tid & 7, co = (tid >> 3) & 15, q4 = tid >> 7;
        int tap = q4 >> 2, quad = q4 & 3;
        int ci = ((j >> 2) << 4) + quad * 4 + (j & 3);   // permuted slot -> true channel
        float v = (co < 3) ? w3[(co * 32 + ci) * 9 + tap] : 0.0f;
        w3p[tid] = bf16s(v);
    }
    if (tid < 1024) {
        int j = tid & 7, co = (tid >> 3) & 31, quad = tid >> 8;
        int k = quad * 8 + j;                             // x-input: unpermuted
        float v = 0.0f;
        if (k < 27) { int tap = (k * 11) >> 5; int ci = k - tap * 3; v = w1[(co * 3 + ci) * 9 + tap]; }
        w1p[tid] = bf16s(v);
    }
}

// ---------------- teps = raw conv1(eps), full image, bf16 [pix][32] true-channel order
__global__ __launch_bounds__(256) void teps_conv1(
    const float* __restrict__ xin, const short* __restrict__ w1p,
    short* __restrict__ outH) {
    const int tile = blockIdx.x;
    const int ty0 = (tile / 10) * 16, tx0 = (tile % 10) * 16;
    const int tid = threadIdx.x;
    const int lane = tid & 63, wv = tid >> 6;
    const int n = lane & 15, quad = lane >> 4;
    __shared__ float sX[3 * 324];
    for (int idx = tid; idx < 3 * 324; idx += 256) {
        int ci = idx / 324, p = idx - ci * 324;
        int ly = p / 18, lx = p - ly * 18;
        int gy = ty0 + ly - 1, gx = tx0 + lx - 1;
        float v = 0.0f;
        if (gy >= 0 && gy < PW && gx >= 0 && gx < PW)
            v = xin[(size_t)ci * PSQ + gy * PW + gx];
        sX[idx] = v;
    }
    __syncthreads();
    int offj[8], valj[8];
    #pragma unroll
    for (int j = 0; j < 8; ++j) {
        int k = quad * 8 + j;
        valj[j] = (k < 27);
        int tap = (k * 11) >> 5; if (k >= 27) tap = 0;
        int ci = k - tap * 3;
        int dy = (tap * 11) >> 5, dx = tap - dy * 3;
        offj[j] = valj[j] ? (ci * 324 + dy * 18 + dx + n) : 0;
    }
    short8 a0 = *(const short8*)&w1p[(quad * 32 + n) * 8];
    short8 a1 = *(const short8*)&w1p[(quad * 32 + 16 + n) * 8];
    #pragma unroll
    for (int r = 0; r < 4; ++r) {
        int row = wv * 4 + r;
        short8 bb;
        #pragma unroll
        for (int j = 0; j < 8; ++j) {
            float v = valj[j] ? sX[offj[j] + row * 18] : 0.0f;
            bb[j] = bf16s(v);
        }
        float4v acc0 = {0.f, 0.f, 0.f, 0.f}, acc1 = {0.f, 0.f, 0.f, 0.f};
        acc0 = __builtin_amdgcn_mfma_f32_16x16x32_bf16(a0, bb, acc0, 0, 0, 0);
        acc1 = __builtin_amdgcn_mfma_f32_16x16x32_bf16(a1, bb, acc1, 0, 0, 0);
        int pix = (ty0 + row) * PW + tx0 + n;
        uint2 h0, h1v;
        h0.x = packbf(acc0[0], acc0[1]); h0.y = packbf(acc0[2], acc0[3]);
        h1v.x = packbf(acc1[0], acc1[1]); h1v.y = packbf(acc1[2], acc1[3]);
        *(uint2*)&outH[(size_t)pix * 32 + quad * 4] = h0;
        *(uint2*)&outH[(size_t)pix * 32 + 16 + quad * 4] = h1v;
    }
}

// ---------------- fully fused RK stage: conv1+conv2+conv3+divergence+RK update
// 10x20 tile; x 16x26, h1 14x24 (336px), h2 12x22 (264px)
// 512 threads (8 waves), LDS 77104 B -> 2 blocks/CU = 4 waves/SIMD; 512-block
// grid = exactly 2/CU. LDS activations stored channel-permuted (c'=quad*8+mt*4+g)
// so each lane's H and D outputs are single 16B ds_write_b128 runs.
__global__ __launch_bounds__(512, 4) void fused_stage(
    const float* __restrict__ xin, float* __restrict__ x0,
    float* __restrict__ xacc, float* __restrict__ xst,
    const short* __restrict__ w1p, const short* __restrict__ w2p,
    const short* __restrict__ w3p, const float* __restrict__ b1,
    const float* __restrict__ b2, const float* __restrict__ b3,
    const float* __restrict__ embr, const short* __restrict__ tepsb,
    const float* __restrict__ epsin, float* __restrict__ Sacc,
    float c1, float c2, float dt, int mode) {
    const int bid = blockIdx.x;             // 0..127
    const int tile = ((bid & 7) << 4) | (bid >> 3);   // XCD-aware swizzle (bijective)
    const int b = blockIdx.y;
    const int oy = (tile >> 3) * TY, ox = (tile & 7) * TX;
    const int tid = threadIdx.x;
    const int lane = tid & 63, wv = tid >> 6;          // wv 0..7
    const int n = lane & 15, quad = lane >> 4;

    __shared__ __align__(16) char smem[77104];
    short* sH1 = (short*)smem;                  // 336*64B = 21504
    short* sD1 = (short*)(smem + 21504);        // 21504
    short* sH2 = (short*)(smem + 43008);        // 264*64B = 16896
    short* sD2 = (short*)(smem + 59904);        // 16896
    short* sX  = (short*)(smem + 43008);        // bf16 x-tile (aliases sH2; dead after ph1)
    float* sOut = (float*)smem;                 // 4800B (ph3+) — aliases sH1 (dead after ph2)
    float* sBE = (float*)(smem + 76800);        // 32 f
    float* sB2 = (float*)(smem + 76928);        // 32 f
    float* sB3 = (float*)(smem + 77056);        // 3 f
    float* wsum = (float*)(smem + 77072);       // 8 f

    // ---- prefetch teps fragments for this block's ph1 iterations (stage-invariant)
    uint2 pt0[3], pt1[3];
    #pragma unroll
    for (int it = 0; it < 3; ++it) {
        int t = wv + it * 8;
        int tt = (t < 21) ? t : 0;
        int p = tt * 16 + n;
        int ry = p / H1W, rx = p - ry * H1W;
        int gy = oy - 2 + ry, gx = ox - 2 + rx;
        int ok = (t < 21) && gy >= 0 && gy < PW && gx >= 0 && gx < PW;
        size_t tbase = ok ? ((size_t)(gy * PW + gx) * 32) : 0;
        pt0[it] = *(const uint2*)&tepsb[tbase + quad * 4];
        pt1[it] = *(const uint2*)&tepsb[tbase + 16 + quad * 4];
    }

    if (tid < 32) { sBE[tid] = b1[tid] + embr[tid]; sB2[tid] = b2[tid]; }
    if (tid < 3) sB3[tid] = b3[tid];

    // ---- stage x region (zero-padded outside image), converted to bf16 once
    for (int idx = tid; idx < 3 * XSZ; idx += 512) {
        int ci = idx / XSZ, p = idx - ci * XSZ;
        int ly = p / XW, lx = p - ly * XW;
        int gy = oy - 3 + ly, gx = ox - 3 + lx;
        float v = 0.0f;
        if (gy >= 0 && gy < PW && gx >= 0 && gx < PW)
            v = xin[(size_t)(b * 3 + ci) * PSQ + gy * PW + gx];
        sX[idx] = bf16s(v);
    }
    __syncthreads();

    // ---- phase 1: conv1 over h1 region (336 px, 21 n-tiles)
    {
        int koff[8], kval[8];
        #pragma unroll
        for (int j = 0; j < 8; ++j) {
            int k = quad * 8 + j;
            kval[j] = (k < 27);
            int tap = (k * 11) >> 5; if (k >= 27) tap = 0;
            int ci = k - tap * 3;
            int dy = (tap * 11) >> 5, dx = tap - dy * 3;
            koff[j] = kval[j] ? (ci * XSZ + dy * XW + dx) : 0;
        }
        short8 a0 = *(const short8*)&w1p[(quad * 32 + n) * 8];
        short8 a1 = *(const short8*)&w1p[(quad * 32 + 16 + n) * 8];
        #pragma unroll
        for (int it = 0; it < 3; ++it) {
            int t = wv + it * 8;
            if (t < 21) {
                int p = t * 16 + n;                // < 336 always
                int ry = p / H1W, rx = p - ry * H1W;
                int gy = oy - 2 + ry, gx = ox - 2 + rx;
                int inimg = (gy >= 0 && gy < PW && gx >= 0 && gx < PW);
                int base = ry * XW + rx;
                short8 bb;
                #pragma unroll
                for (int j = 0; j < 8; ++j)
                    bb[j] = kval[j] ? sX[koff[j] + base] : (short)0;
                float4v acc0 = {0.f, 0.f, 0.f, 0.f}, acc1 = {0.f, 0.f, 0.f, 0.f};
                acc0 = __builtin_amdgcn_mfma_f32_16x16x32_bf16(a0, bb, acc0, 0, 0, 0);
                acc1 = __builtin_amdgcn_mfma_f32_16x16x32_bf16(a1, bb, acc1, 0, 0, 0);
                int swz = (p & 7) << 4;
                unsigned hq[4], dq[4];
                #pragma unroll
                for (int mt = 0; mt < 2; ++mt) {
                    float4v* ac = mt ? &acc1 : &acc0;
                    uint2 t2 = mt ? pt1[it] : pt0[it];
                    int co0 = mt * 16 + quad * 4;
                    unsigned ts4[4] = {t2.x & 0xFFFFu, t2.x >> 16, t2.y & 0xFFFFu, t2.y >> 16};
                    unsigned hv[4], dv[4];
                    #pragma unroll
                    for (int g = 0; g < 4; ++g) {
                        float pre = (*ac)[g] + sBE[co0 + g];
                        hv[g] = inimg ? (unsigned)(unsigned short)bf16s(fmaxf(pre, 0.0f)) : 0u;
                        dv[g] = (inimg && pre > 0.0f) ? ts4[g] : 0u;
                    }
                    hq[mt * 2]     = hv[0] | (hv[1] << 16);
                    hq[mt * 2 + 1] = hv[2] | (hv[3] << 16);
                    dq[mt * 2]     = dv[0] | (dv[1] << 16);
                    dq[mt * 2 + 1] = dv[2] | (dv[3] << 16);
                }
                int byw = ((p << 6) | (quad << 4)) ^ swz;
                uint4 H4 = {hq[0], hq[1], hq[2], hq[3]};
                uint4 D4 = {dq[0], dq[1], dq[2], dq[3]};
                *(uint4*)((char*)sH1 + byw) = H4;
                *(uint4*)((char*)sD1 + byw) = D4;
            }
        }
    }
    __syncthreads();

    // ---- phase 2: conv2 over h2 region (264 px, 17 n-tiles), 4-chain ILP
    {
        short8 a2[9][2];
        #pragma unroll
        for (int tap = 0; tap < 9; ++tap) {
            a2[tap][0] = *(const short8*)&w2p[((tap * 4 + quad) * 32 + n) * 8];
            a2[tap][1] = *(const short8*)&w2p[((tap * 4 + quad) * 32 + 16 + n) * 8];
        }
        for (int t = wv; t < 17; t += 8) {
            int p = t * 16 + n;
            int pc = p < H2N ? p : (H2N - 1);
            int ry = pc / H2W, rx = pc - ry * H2W;
            float4v aP0 = {0.f,0.f,0.f,0.f}, aP1 = {0.f,0.f,0.f,0.f};
            float4v aD0 = {0.f,0.f,0.f,0.f}, aD1 = {0.f,0.f,0.f,0.f};
            #pragma unroll
            for (int tap = 0; tap < 9; ++tap) {
                int dy = (tap * 11) >> 5, dx = tap - dy * 3;
                int q = (ry + dy) * H1W + rx + dx;
                int byr = ((q << 6) | (quad << 4)) ^ ((q & 7) << 4);
                short8 bp = *(const short8*)((const char*)sH1 + byr);
                short8 bd = *(const short8*)((const char*)sD1 + byr);
                aP0 = __builtin_amdgcn_mfma_f32_16x16x32_bf16(a2[tap][0], bp, aP0, 0, 0, 0);
                aP1 = __builtin_amdgcn_mfma_f32_16x16x32_bf16(a2[tap][1], bp, aP1, 0, 0, 0);
                aD0 = __builtin_amdgcn_mfma_f32_16x16x32_bf16(a2[tap][0], bd, aD0, 0, 0, 0);
                aD1 = __builtin_amdgcn_mfma_f32_16x16x32_bf16(a2[tap][1], bd, aD1, 0, 0, 0);
            }
            int gy = oy - 1 + ry, gx = ox - 1 + rx;
            int inimg = (gy >= 0 && gy < PW && gx >= 0 && gx < PW);
            if (p < H2N) {
                int swz = (p & 7) << 4;
                unsigned hq[4], dq[4];
                #pragma unroll
                for (int mt = 0; mt < 2; ++mt) {
                    float4v* acP = mt ? &aP1 : &aP0;
                    float4v* acD = mt ? &aD1 : &aD0;
                    int co0 = mt * 16 + quad * 4;
                    unsigned hv[4], dv[4];
                    #pragma unroll
                    for (int g = 0; g < 4; ++g) {
                        float pre = (*acP)[g] + sB2[co0 + g];
                        hv[g] = inimg ? (unsigned)(unsigned short)bf16s(fmaxf(pre, 0.0f)) : 0u;
                        dv[g] = (inimg && pre > 0.0f) ? (unsigned)(unsigned short)bf16s((*acD)[g]) : 0u;
                    }
                    hq[mt * 2]     = hv[0] | (hv[1] << 16);
                    hq[mt * 2 + 1] = hv[2] | (hv[3] << 16);
                    dq[mt * 2]     = dv[0] | (dv[1] << 16);
                    dq[mt * 2 + 1] = dv[2] | (dv[3] << 16);
                }
                int byw = ((p << 6) | (quad << 4)) ^ swz;
                uint4 H4 = {hq[0], hq[1], hq[2], hq[3]};
                uint4 D4 = {dq[0], dq[1], dq[2], dq[3]};
                *(uint4*)((char*)sH2 + byw) = H4;
                *(uint4*)((char*)sD2 + byw) = D4;
            }
        }
    }
    __syncthreads();

    // ---- prefetch final-phase operands now (covered by ph3's MFMA work)
    float pf_x[2], pf_e[2], pf_a[2], pf_x0[2];
    #pragma unroll
    for (int rep = 0; rep < 2; ++rep) {
        int idx = tid + rep * 512;
        int v = (idx < 3 * OUTN);
        int idc = v ? idx : 0;
        int c = idc / OUTN, pp = idc - c * OUTN;
        int ry = pp / TX, rx = pp - ry * TX;
        int pix = (oy + ry) * PW + ox + rx;
        size_t gi = (size_t)(b * 3 + c) * PSQ + pix;
        pf_x[rep] = v ? xin[gi] : 0.0f;
        pf_e[rep] = v ? epsin[c * PSQ + pix] : 0.0f;
        pf_a[rep] = 0.0f; pf_x0[rep] = 0.0f;
        if (mode >= 1) {
            pf_a[rep] = v ? xacc[gi] : 0.0f;
            pf_x0[rep] = v ? x0[gi] : 0.0f;
        }
    }

    // ---- phase 3: conv3 over out tile (200 px, 13 n-tiles) -> sOut
    {
        short8 a3[9];
        #pragma unroll
        for (int tap = 0; tap < 9; ++tap)
            a3[tap] = *(const short8*)&w3p[((tap * 4 + quad) * 16 + n) * 8];
        for (int t = wv; t < 13; t += 8) {
            int p = t * 16 + n;
            int pc = p < OUTN ? p : (OUTN - 1);
            int ry = pc / TX, rx = pc - ry * TX;
            float4v aP = {0.f,0.f,0.f,0.f}, aD = {0.f,0.f,0.f,0.f};
            #pragma unroll
            for (int tap = 0; tap < 9; ++tap) {
                int dy = (tap * 11) >> 5, dx = tap - dy * 3;
                int q = (ry + dy) * H2W + rx + dx;
                int byr = ((q << 6) | (quad << 4)) ^ ((q & 7) << 4);
                short8 bp = *(const short8*)((const char*)sH2 + byr);
                short8 bd = *(const short8*)((const char*)sD2 + byr);
                aP = __builtin_amdgcn_mfma_f32_16x16x32_bf16(a3[tap], bp, aP, 0, 0, 0);
                aD = __builtin_amdgcn_mfma_f32_16x16x32_bf16(a3[tap], bd, aD, 0, 0, 0);
            }
            if (quad == 0 && p < OUTN) {
                #pragma unroll
                for (int c = 0; c < 3; ++c) {
                    sOut[c * OUTN + p] = aP[c] + sB3[c];
                    sOut[3 * OUTN + c * OUTN + p] = aD[c];
                }
            }
        }
    }
    __syncthreads();

    // ---- final: drift + RK update + divergence, all 512 threads, prefetched ops
    float s = 0.0f;
    #pragma unroll
    for (int rep = 0; rep < 2; ++rep) {
        int idx = tid + rep * 512;
        if (idx < 3 * OUTN) {
            int c = idx / OUTN, pp = idx - c * OUTN;
            int ry = pp / TX, rx = pp - ry * TX;
            int pix = (oy + ry) * PW + ox + rx;
            size_t gi = (size_t)(b * 3 + c) * PSQ + pix;
            float y = sOut[c * OUTN + pp];
            float d = sOut[3 * OUTN + c * OUTN + pp];
            float xv = pf_x[rep];
            float k = -c1 * xv - c2 * y;
            if (mode == 0) {
                xacc[gi] = k;
                xst[gi] = xv + 0.5f * dt * k;     // xin == x0 at stage 0
            } else if (mode == 1) {
                xacc[gi] = pf_a[rep] + 2.0f * k;
                xst[gi] = pf_x0[rep] + 0.5f * dt * k;
            } else if (mode == 2) {
                xacc[gi] = pf_a[rep] + 2.0f * k;
                xst[gi] = pf_x0[rep] + dt * k;
            } else {
                x0[gi] = pf_x0[rep] + (dt / 6.0f) * (pf_a[rep] + k);
            }
            s += d * pf_e[rep];
        }
    }
    #pragma unroll
    for (int off = 32; off > 0; off >>= 1) s += __shfl_down(s, off);
    if (lane == 0) wsum[wv] = s;
    __syncthreads();
    if (tid == 0) {
        float tot = 0.0f;
        #pragma unroll
        for (int w = 0; w < 8; ++w) tot += wsum[w];
        atomicAdd(&Sacc[b], tot);
    }
}

// ---------------- sum z^2 per batch (parallel over 25 segments)
__global__ void sumz2_kernel(const float* __restrict__ x0, float* __restrict__ sumz2) {
    int b = blockIdx.x, seg = blockIdx.y, tid = threadIdx.x;
    const float* p = x0 + (size_t)b * NDIM + seg * 3072;
    float s = 0.0f;
    for (int i = tid; i < 3072; i += 256) { float v = p[i]; s += v * v; }
    #pragma unroll
    for (int off = 32; off > 0; off >>= 1) s += __shfl_down(s, off);
    __shared__ float wsum[4];
    if ((tid & 63) == 0) wsum[tid >> 6] = s;
    __syncthreads();
    if (tid == 0) atomicAdd(&sumz2[b], wsum[0] + wsum[1] + wsum[2] + wsum[3]);
}

// ---------------- final bpd
__global__ void bpd_kernel(const float* __restrict__ S, const float* __restrict__ sumz2,
                           float* __restrict__ out, MC40 mc) {
    int b = threadIdx.x;
    if (b >= NB) return;
    float lp = mc.A;
    for (int r = 0; r < 40; r++) lp -= mc.m[r] * S[r * 4 + b];
    float prior = -70574.479354f - 0.5f * sumz2[b];
    out[b] = -(prior + lp) * 1.8785164100960743e-5f;
}

extern "C" void kernel_launch(void* const* d_in, const int* in_sizes, int n_in,
                              void* d_out, int out_size, void* d_ws, size_t ws_size,
                              hipStream_t stream) {
    const float* patches = (const float*)d_in[0];
    const float* epsin = (const float*)d_in[1];
    const float* w1 = (const float*)d_in[2];
    const float* b1 = (const float*)d_in[3];
    const float* wt = (const float*)d_in[4];
    const float* bt = (const float*)d_in[5];
    const float* w2 = (const float*)d_in[6];
    const float* b2 = (const float*)d_in[7];
    const float* w3 = (const float*)d_in[8];
    const float* b3 = (const float*)d_in[9];
    float* outp = (float*)d_out;
    char* wsb = (char*)d_ws;

    float* Sbuf  = (float*)(wsb + 0);          // 160 f
    float* sumz2 = (float*)(wsb + 640);        // 4 f
    float* emb   = (float*)(wsb + 1024);       // 1280 f
    short* w1p   = (short*)(wsb + 6144);       // 1024 bf16
    short* w2p   = (short*)(wsb + 8192);       // 9216 bf16
    short* w3p   = (short*)(wsb + 26624);      // 4608 bf16
    short* tepsb = (short*)(wsb + 36864);      // 819200 bf16
    float* x0    = (float*)(wsb + 1675264);    // NX f
    float* xacc  = (float*)(wsb + 2904064);
    float* xst   = (float*)(wsb + 4132864);    // end ~5.4 MB

    const double dt = (1.0 - 1e-5) / 10.0;
    TS40 ts; MC40 mc;
    float c1a[40], c2a[40];
    double A = 0.0;
    const double wgt[4] = {1.0, 2.0, 2.0, 1.0};
    for (int i = 0; i < 10; i++) {
        double t0 = 1e-5 + dt * i;
        double tr[4] = {t0, t0 + 0.5 * dt, t0 + 0.5 * dt, t0 + dt};
        for (int s = 0; s < 4; s++) {
            int r = i * 4 + s;
            double t = tr[s];
            double beta = 0.1 + 19.9 * t;
            double lmc = -0.25 * t * t * 19.9 - 0.05 * t;
            double stdv = 1.0 - exp(2.0 * lmc);
            double g2 = beta * (1.0 - exp(4.0 * lmc));
            double c2 = 0.5 * g2 / stdv;
            ts.t[r] = (float)t;
            c1a[r] = (float)(0.5 * beta);
            c2a[r] = (float)c2;
            double coef = dt / 6.0 * wgt[s];
            mc.m[r] = (float)(coef * c2);
            A += coef * (-0.5 * beta * (double)NDIM);
        }
    }
    mc.A = (float)A;

    hipMemsetAsync(wsb, 0, 656, stream);  // Sbuf + sumz2
    hipMemcpyAsync(x0, patches, NX * sizeof(float), hipMemcpyDeviceToDevice, stream);

    emb_kernel<<<40, 64, 0, stream>>>(wt, bt, emb, ts);
    repack_kernel<<<36, 256, 0, stream>>>(w1, w2, w3, w1p, w2p, w3p);
    teps_conv1<<<100, 256, 0, stream>>>(epsin, w1p, tepsb);

    for (int i = 0; i < 10; i++) {
        for (int s = 0; s < 4; s++) {
            int r = i * 4 + s;
            const float* xin = (s == 0) ? x0 : xst;
            fused_stage<<<dim3(128, NB), 512, 0, stream>>>(
                xin, x0, xacc, xst, w1p, w2p, w3p, b1, b2, b3,
                emb + r * 32, tepsb, epsin, Sbuf + r * 4,
                c1a[r], c2a[r], (float)dt, s);
        }
    }
    sumz2_kernel<<<dim3(NB, 25), 256, 0, stream>>>(x0, sumz2);
    bpd_kernel<<<1, 64, 0, stream>>>(Sbuf, sumz2, outp, mc);
}